// Round 3
// baseline (51356.506 us; speedup 1.0000x reference)
//
#include <hip/hip_runtime.h>
#include <hip/hip_bf16.h>

// ---------------------------------------------------------------------------
// Lattice LSTM (bidirectional) — round 2: single-CU-per-direction scan with
// register-resident bf16 weights + MFMA matvecs. No cross-CU sync at all.
//
//   k_embed     : xg = x@W_ih + b (bf16), xa = x@aW_ih + ab (f32)   [parallel]
//   k_wordgates : wg = word_emb@wW_ih + wb (bf16)                   [parallel]
//   k_scan      : grid=2 (one block/CU per direction), 1024 threads = 16 waves.
//                 Gate weights [W_hh | wW_hh] (256x1536) live in VGPRs as MFMA
//                 B-fragments (192 regs/wave); aW_hh on waves 0-7 (64 regs).
//                 Per step: A = [h_{t-1}; h_start(w)...] 16x256 bf16 in LDS ->
//                 48 MFMAs/wave -> word cells -> alpha MFMA -> merge. 5
//                 __syncthreads per step; inputs prefetched one step ahead.
//   k_proj      : out = concat(hf, hb_flipped) @ W_lin + b_lin.
// ---------------------------------------------------------------------------

#define TSEQ 2048
#define KEND 8
#define DEMB 100
#define H    256
#define H3   768
#define WD   300
#define CCLS 18
#define NTH  1024

typedef __attribute__((ext_vector_type(8))) short bf16x8;
typedef __attribute__((ext_vector_type(4))) float f32x4;

// LDS offsets (bytes)
#define LO_A     0        // A   bf16 [16][256] XOR-swizzled        8192
#define LO_A2    8192     // A2  bf16 [16][256] XOR-swizzled        8192
#define LO_RC    16384    // ringC f32 [8][256]                     8192
#define LO_RHB   24576    // ringHb u16 [8][256]                    4096
#define LO_PRE   28672    // preS f32 [768]                         3072
#define LO_PW    31744    // pwS  f32 [8][768]                     24576
#define LO_CW    56320    // cwS  f32 [8][256]                      8192
#define LO_AW    64512    // awS  f32 [8][256]                      8192
#define LO_WG    72704    // wgStage u16 [2][8][768]               24576
#define LO_META  97280    // int [2][32]: {nw, wSlot[8], wStart[8]}  256
#define SMEM_SCAN 97536

__device__ __forceinline__ float sigf(float x) { return 1.0f / (1.0f + expf(-x)); }
__device__ __forceinline__ float bf2f(unsigned short u) { return __uint_as_float(((unsigned)u) << 16); }
__device__ __forceinline__ short f2bf(float f) {
  union { float f; unsigned u; } x; x.f = f;
  unsigned r = x.u + 0x7fffu + ((x.u >> 16) & 1u);   // RNE
  return (short)(r >> 16);
}

// ---------------- K1: char embedding -> gate / alpha input preacts ----------
__global__ __launch_bounds__(256) void k_embed(
    const int* __restrict__ inputs, const float* __restrict__ E,
    const float* __restrict__ W_ih_f, const float* __restrict__ b_f,
    const float* __restrict__ aW_ih_f, const float* __restrict__ ab_f,
    const float* __restrict__ W_ih_b, const float* __restrict__ b_b,
    const float* __restrict__ aW_ih_b, const float* __restrict__ ab_b,
    __hip_bfloat16* __restrict__ xg, float* __restrict__ xa)
{
  const int t = blockIdx.x, dir = blockIdx.y;
  const int tid = threadIdx.x;
  const float* W_ih = dir ? W_ih_b : W_ih_f;
  const float* bb   = dir ? b_b    : b_f;
  const float* aW   = dir ? aW_ih_b : aW_ih_f;
  const float* ab   = dir ? ab_b   : ab_f;
  const int src = dir ? (TSEQ - 1 - t) : t;

  __shared__ float xr[DEMB];
  if (tid < DEMB) xr[tid] = E[(size_t)inputs[src] * DEMB + tid];
  __syncthreads();

  float a0 = bb[tid], a1 = bb[H + tid], a2 = bb[2 * H + tid], a3 = ab[tid];
  for (int r = 0; r < DEMB; r += 4) {
    const float4 e4 = *reinterpret_cast<const float4*>(&xr[r]);
    const float ev[4] = {e4.x, e4.y, e4.z, e4.w};
#pragma unroll
    for (int kk = 0; kk < 4; ++kk) {
      const float* wp = W_ih + (size_t)(r + kk) * H3 + tid;
      a0 += ev[kk] * wp[0];
      a1 += ev[kk] * wp[H];
      a2 += ev[kk] * wp[2 * H];
      a3 += ev[kk] * aW[(size_t)(r + kk) * H + tid];
    }
  }
  __hip_bfloat16* xgrow = xg + ((size_t)dir * TSEQ + t) * H3;
  xgrow[tid]         = __float2bfloat16(a0);
  xgrow[H + tid]     = __float2bfloat16(a1);
  xgrow[2 * H + tid] = __float2bfloat16(a2);
  xa[((size_t)dir * TSEQ + t) * H + tid] = a3;
}

// ---------------- K2: word-gate preacts (valid slots only), bf16 out --------
__global__ __launch_bounds__(256) void k_wordgates(
    const int* __restrict__ fw_ids, const int* __restrict__ fw_mask,
    const int* __restrict__ bw_ids, const int* __restrict__ bw_mask,
    const float* __restrict__ word_table,
    const float* __restrict__ wW_ih_f, const float* __restrict__ wb_f,
    const float* __restrict__ wW_ih_b, const float* __restrict__ wb_b,
    __hip_bfloat16* __restrict__ wg)
{
  const int t = blockIdx.x, dir = blockIdx.y;
  const int tid = threadIdx.x;
  const int* ids = (dir ? bw_ids : fw_ids) + t * KEND;
  const int* msk = (dir ? bw_mask : fw_mask) + t * KEND;
  const float* wW = dir ? wW_ih_b : wW_ih_f;
  const float* wb = dir ? wb_b    : wb_f;

  __shared__ float we[KEND][WD];
  for (int w = 0; w < KEND; ++w) {
    if (msk[w]) {
      const float* src = word_table + (size_t)ids[w] * WD;
      for (int i = tid; i < WD; i += 256) we[w][i] = src[i];
    }
  }
  __syncthreads();

  __hip_bfloat16* out = wg + ((size_t)dir * TSEQ + t) * KEND * H3;
  for (int w = 0; w < KEND; ++w) {
    if (!msk[w]) continue;
    float a0 = wb[tid], a1 = wb[H + tid], a2 = wb[2 * H + tid];
    for (int r = 0; r < WD; r += 4) {
      const float4 e4 = *reinterpret_cast<const float4*>(&we[w][r]);
      const float ev[4] = {e4.x, e4.y, e4.z, e4.w};
#pragma unroll
      for (int kk = 0; kk < 4; ++kk) {
        const float* wp = wW + (size_t)(r + kk) * H3 + tid;
        a0 += ev[kk] * wp[0];
        a1 += ev[kk] * wp[H];
        a2 += ev[kk] * wp[2 * H];
      }
    }
    out[w * H3 + tid]         = __float2bfloat16(a0);
    out[w * H3 + H + tid]     = __float2bfloat16(a1);
    out[w * H3 + 2 * H + tid] = __float2bfloat16(a2);
  }
}

// ---------------- K3: single-CU MFMA scan, 1 block per direction ------------
__global__ __launch_bounds__(NTH, 4) void k_scan(
    const __hip_bfloat16* __restrict__ xg, const float* __restrict__ xa,
    const __hip_bfloat16* __restrict__ wg, float* __restrict__ hseq,
    const int* __restrict__ fw_start, const int* __restrict__ fw_mask,
    const int* __restrict__ bw_start, const int* __restrict__ bw_mask,
    const float* __restrict__ W_hh_f, const float* __restrict__ aW_hh_f, const float* __restrict__ wW_hh_f,
    const float* __restrict__ W_hh_b, const float* __restrict__ aW_hh_b, const float* __restrict__ wW_hh_b)
{
  extern __shared__ char smem[];
  char* Abuf  = smem + LO_A;
  char* A2buf = smem + LO_A2;
  float* ringC = (float*)(smem + LO_RC);
  unsigned short* ringHb = (unsigned short*)(smem + LO_RHB);
  float* preS = (float*)(smem + LO_PRE);
  float* pwS  = (float*)(smem + LO_PW);
  float* cwS  = (float*)(smem + LO_CW);
  float* awS  = (float*)(smem + LO_AW);
  int*   metaI = (int*)(smem + LO_META);

  const int tid  = threadIdx.x;
  const int dir  = blockIdx.x;
  const int lane = tid & 63;
  const int wv   = tid >> 6;          // wave 0..15
  const int lmod = lane & 15;         // MFMA row/col index
  const int lgrp = lane >> 4;         // MFMA k-group

  const int* startA = dir ? bw_start : fw_start;
  const int* maskA  = dir ? bw_mask  : fw_mask;
  const float* W_hh  = dir ? W_hh_b  : W_hh_f;
  const float* aW_hh = dir ? aW_hh_b : aW_hh_f;
  const float* wW_hh = dir ? wW_hh_b : wW_hh_f;

  // ---- one-time: B fragments into registers (bf16) -------------------------
  // k-map for both A and B: k = ks*32 + lgrp*8 + e  (any consistent bijection
  // of k is correct for D=A*B; C/D layout is the m89 HW-verified one).
  bf16x8 bW[6][8];                    // gate cols: wave wv owns tiles wv*6..wv*6+5 of N=1536
#pragma unroll
  for (int n = 0; n < 6; ++n) {
    const int c = (wv * 6 + n) * 16 + lmod;
    const float* src = (c < H3) ? W_hh : wW_hh;
    const int cc = (c < H3) ? c : c - H3;
#pragma unroll
    for (int ks = 0; ks < 8; ++ks) {
      bf16x8 f;
#pragma unroll
      for (int e = 0; e < 8; ++e)
        f[e] = f2bf(src[(size_t)(ks * 32 + lgrp * 8 + e) * H3 + cc]);
      bW[n][ks] = f;
    }
  }
  bf16x8 bA[2][8];                    // alpha cols: waves 0-7 own 2 tiles each of N=256
  if (wv < 8) {
#pragma unroll
    for (int n = 0; n < 2; ++n) {
      const int c = (wv * 2 + n) * 16 + lmod;
#pragma unroll
      for (int ks = 0; ks < 8; ++ks) {
        bf16x8 f;
#pragma unroll
        for (int e = 0; e < 8; ++e)
          f[e] = f2bf(aW_hh[(size_t)(ks * 32 + lgrp * 8 + e) * H + c]);
        bA[n][ks] = f;
      }
    }
  }

  // ---- prologue: zero state, prefetch t=0, stage it ------------------------
  for (int o = tid * 16; o < 8192; o += NTH * 16) {
    *(uint4*)(Abuf + o)  = uint4{0, 0, 0, 0};
    *(uint4*)(A2buf + o) = uint4{0, 0, 0, 0};
    *(uint4*)((char*)ringC + o) = uint4{0, 0, 0, 0};
  }
  for (int o = tid * 16; o < 4096; o += NTH * 16)
    *(uint4*)((char*)ringHb + o) = uint4{0, 0, 0, 0};

  // prefetch registers
  unsigned short nxI = 0, nxO = 0, nxG = 0;  float nxA = 0.f;
  unsigned short cxI = 0, cxO = 0, cxG = 0;  float cxA = 0.f;
  uint4 wgPf = uint4{0, 0, 0, 0};
  int nmt = 0;

  // issue prefetch for t=0
  {
    const int tn = 0;
    if (tid < H) {
      const unsigned short* xr = (const unsigned short*)(xg + ((size_t)dir * TSEQ + tn) * H3);
      nxI = xr[tid]; nxO = xr[H + tid]; nxG = xr[2 * H + tid];
      nxA = xa[((size_t)dir * TSEQ + tn) * H + tid];
    }
    if (tid < 768)
      wgPf = *(const uint4*)((const char*)(wg + ((size_t)dir * TSEQ + tn) * KEND * H3) + tid * 16);
    if (wv == 15) {
      if (lane < 8) nmt = maskA[tn * KEND + lane];
      else if (lane < 16) nmt = startA[tn * KEND + (lane - 8)];
    }
  }
  __syncthreads();   // zeros visible
  // stage t=0 into parity 0
  if (tid < 768) *(uint4*)(smem + LO_WG + 0 * 12288 + tid * 16) = wgPf;
  if (wv == 15) {
    int mAll[8], sAll[8];
#pragma unroll
    for (int s = 0; s < 8; ++s) { mAll[s] = __shfl(nmt, s); sAll[s] = __shfl(nmt, 8 + s); }
    if (lane == 0) {
      int* mp = metaI;
      int n = 0;
      for (int s = 0; s < 8; ++s)
        if (mAll[s]) { mp[1 + n] = s; mp[9 + n] = sAll[s]; ++n; }
      mp[0] = n;
    }
  }
  cxI = nxI; cxO = nxO; cxG = nxG; cxA = nxA;
  __syncthreads();

  // ---- main loop ------------------------------------------------------------
  for (int t = 0; t < TSEQ; ++t) {
    const int par = t & 1;
    const int* mp = metaI + par * 32;
    const int nw = mp[0];

    // S0: build A word rows (row w+1 <- ringHb[start_w]) + issue prefetch t+1
    for (int u = tid; u < nw * 128; u += NTH) {
      const int w = u >> 7, j2 = u & 127;
      const int slot = mp[9 + w] & 7;
      const unsigned val = *(const unsigned*)(ringHb + slot * 256 + j2 * 2);
      *(unsigned*)(Abuf + ((w + 1) * 512 + ((j2 * 4) ^ (((w + 1) & 7) << 4)))) = val;
    }
    {
      const int tn = (t + 1 < TSEQ) ? t + 1 : TSEQ - 1;
      if (tid < H) {
        const unsigned short* xr = (const unsigned short*)(xg + ((size_t)dir * TSEQ + tn) * H3);
        nxI = xr[tid]; nxO = xr[H + tid]; nxG = xr[2 * H + tid];
        nxA = xa[((size_t)dir * TSEQ + tn) * H + tid];
      }
      if (tid < 768)
        wgPf = *(const uint4*)((const char*)(wg + ((size_t)dir * TSEQ + tn) * KEND * H3) + tid * 16);
      if (wv == 15) {
        if (lane < 8) nmt = maskA[tn * KEND + lane];
        else if (lane < 16) nmt = startA[tn * KEND + (lane - 8)];
      }
    }
    __syncthreads();   // sync1: A ready

    // S1: gate MFMAs (char cols on waves 0-7, word cols on waves 8-15)
    if (!(wv >= 8 && nw == 0)) {
      f32x4 acc[6];
#pragma unroll
      for (int n = 0; n < 6; ++n) acc[n] = f32x4{0.f, 0.f, 0.f, 0.f};
#pragma unroll
      for (int ks = 0; ks < 8; ++ks) {
        const bf16x8 av = *(const bf16x8*)(Abuf + (lmod * 512 + ((ks * 64 + lgrp * 16) ^ ((lmod & 7) << 4))));
#pragma unroll
        for (int n = 0; n < 6; ++n)
          acc[n] = __builtin_amdgcn_mfma_f32_16x16x32_bf16(av, bW[n][ks], acc[n], 0, 0, 0);
      }
      if (wv < 8) {
        if (lane < 16) {
#pragma unroll
          for (int n = 0; n < 6; ++n) preS[(wv * 6 + n) * 16 + lane] = acc[n][0];
        }
      } else {
        const unsigned short* wgRow = (const unsigned short*)(smem + LO_WG + par * 12288);
#pragma unroll
        for (int n = 0; n < 6; ++n) {
          const int colL = (wv - 8) * 96 + n * 16 + lmod;
#pragma unroll
          for (int r = 0; r < 4; ++r) {
            const int row = lgrp * 4 + r;
            if (row >= 1 && row <= nw) {
              const int slot = mp[1 + (row - 1)];
              pwS[(row - 1) * 768 + colL] = acc[n][r] + bf2f(wgRow[slot * 768 + colL]);
            }
          }
        }
      }
    }
    __syncthreads();   // sync2: preS/pwS ready

    // S2: word cells cw = sig(wf)*c_start + sig(wi)*tanh(wg); write cwS + A2
    if (nw > 0) {
      for (int u = tid; u < nw * 256; u += NTH) {
        const int w = u >> 8, j = u & 255;
        const float wi  = pwS[w * 768 + j];
        const float wf  = pwS[w * 768 + 256 + j];
        const float wgg = pwS[w * 768 + 512 + j];
        const int slot = mp[9 + w] & 7;
        const float cs = ringC[slot * 256 + j];
        const float cv = sigf(wf) * cs + sigf(wi) * tanhf(wgg);
        cwS[w * 256 + j] = cv;
        *(unsigned short*)(A2buf + (w * 512 + ((j * 2) ^ ((w & 7) << 4)))) = (unsigned short)f2bf(cv);
      }
    }
    __syncthreads();   // sync3: cwS/A2 ready

    // S3: alpha matvec (waves 0-7), awS[w][j] = (cw @ aW_hh)[w][j]
    if (nw > 0 && wv < 8) {
      f32x4 acc2[2];
#pragma unroll
      for (int n = 0; n < 2; ++n) acc2[n] = f32x4{0.f, 0.f, 0.f, 0.f};
#pragma unroll
      for (int ks = 0; ks < 8; ++ks) {
        const bf16x8 av = *(const bf16x8*)(A2buf + (lmod * 512 + ((ks * 64 + lgrp * 16) ^ ((lmod & 7) << 4))));
#pragma unroll
        for (int n = 0; n < 2; ++n)
          acc2[n] = __builtin_amdgcn_mfma_f32_16x16x32_bf16(av, bA[n][ks], acc2[n], 0, 0, 0);
      }
#pragma unroll
      for (int n = 0; n < 2; ++n) {
        const int colL = (wv * 2 + n) * 16 + lmod;
#pragma unroll
        for (int r = 0; r < 4; ++r) {
          const int row = lgrp * 4 + r;
          if (row < nw) awS[row * 256 + colL] = acc2[n][r];
        }
      }
    }
    __syncthreads();   // sync4: awS ready

    // S4: merge + state update (threads 0-255) ; stage t+1 ; meta compact t+1
    if (tid < H) {
      const int j = tid;
      const float i_s = sigf(bf2f(cxI) + preS[j]);
      const float o_s = sigf(bf2f(cxO) + preS[256 + j]);
      const float g_t = tanhf(bf2f(cxG) + preS[512 + j]);
      float cnew;
      if (nw > 0) {
        const float e_i = expf(i_s);
        float num = e_i * g_t, den = e_i;
        for (int w = 0; w < nw; ++w) {
          const float a  = sigf(cxA + awS[w * 256 + j]);
          const float ea = expf(a);
          num += ea * cwS[w * 256 + j];
          den += ea;
        }
        cnew = num / den;
      } else {
        cnew = (1.f - i_s) * ringC[((t - 1) & 7) * 256 + j] + i_s * g_t;
      }
      const float hnew = o_s * tanhf(cnew);
      ringC[(t & 7) * 256 + j] = cnew;
      const unsigned short hb = (unsigned short)f2bf(hnew);
      ringHb[(t & 7) * 256 + j] = hb;
      *(unsigned short*)(Abuf + (j * 2)) = hb;           // A row 0 (no swizzle for row 0)
      hseq[((size_t)dir * TSEQ + t) * H + j] = hnew;
    }
    if (tid < 768) *(uint4*)(smem + LO_WG + (par ^ 1) * 12288 + tid * 16) = wgPf;
    if (wv == 15) {
      int mAll[8], sAll[8];
#pragma unroll
      for (int s = 0; s < 8; ++s) { mAll[s] = __shfl(nmt, s); sAll[s] = __shfl(nmt, 8 + s); }
      if (lane == 0) {
        int* mq = metaI + (par ^ 1) * 32;
        int n = 0;
        for (int s = 0; s < 8; ++s)
          if (mAll[s]) { mq[1 + n] = s; mq[9 + n] = sAll[s]; ++n; }
        mq[0] = n;
      }
    }
    cxI = nxI; cxO = nxO; cxG = nxG; cxA = nxA;
    __syncthreads();   // sync5: ring/stage/meta ready for t+1
  }
}

// ---------------- K4: output projection -------------------------------------
__global__ __launch_bounds__(64) void k_proj(
    const float* __restrict__ hseq, const float* __restrict__ W_lin,
    const float* __restrict__ b_lin, float* __restrict__ out)
{
  const int t = blockIdx.x;
  const int tid = threadIdx.x;
  __shared__ float hrow[2 * H];
  for (int i = tid; i < H; i += 64) {
    hrow[i]     = hseq[(size_t)t * H + i];
    hrow[H + i] = hseq[((size_t)TSEQ + (TSEQ - 1 - t)) * H + i];
  }
  __syncthreads();
  if (tid < CCLS) {
    float acc = b_lin[tid];
    for (int j = 0; j < 2 * H; ++j) acc += hrow[j] * W_lin[(size_t)j * CCLS + tid];
    out[(size_t)t * CCLS + tid] = acc;
  }
}

// ---------------------------------------------------------------------------
extern "C" void kernel_launch(void* const* d_in, const int* in_sizes, int n_in,
                              void* d_out, int out_size, void* d_ws, size_t ws_size,
                              hipStream_t stream)
{
  const int* inputs   = (const int*)d_in[0];
  const int* fw_ids   = (const int*)d_in[1];
  const int* fw_start = (const int*)d_in[2];
  const int* fw_mask  = (const int*)d_in[3];
  const int* bw_ids   = (const int*)d_in[4];
  const int* bw_start = (const int*)d_in[5];
  const int* bw_mask  = (const int*)d_in[6];
  const float* E          = (const float*)d_in[8];
  const float* word_table = (const float*)d_in[9];
  const float* W_lin      = (const float*)d_in[10];
  const float* b_lin      = (const float*)d_in[11];
  const float* fw_W_ih  = (const float*)d_in[12];
  const float* fw_W_hh  = (const float*)d_in[13];
  const float* fw_b     = (const float*)d_in[14];
  const float* fw_aW_ih = (const float*)d_in[15];
  const float* fw_aW_hh = (const float*)d_in[16];
  const float* fw_ab    = (const float*)d_in[17];
  const float* fw_wW_ih = (const float*)d_in[18];
  const float* fw_wW_hh = (const float*)d_in[19];
  const float* fw_wb    = (const float*)d_in[20];
  const float* bw_W_ih  = (const float*)d_in[21];
  const float* bw_W_hh  = (const float*)d_in[22];
  const float* bw_b     = (const float*)d_in[23];
  const float* bw_aW_ih = (const float*)d_in[24];
  const float* bw_aW_hh = (const float*)d_in[25];
  const float* bw_ab    = (const float*)d_in[26];
  const float* bw_wW_ih = (const float*)d_in[27];
  const float* bw_wW_hh = (const float*)d_in[28];
  const float* bw_wb    = (const float*)d_in[29];

  char* p = (char*)d_ws;
  __hip_bfloat16* xg = (__hip_bfloat16*)p;  p += (size_t)2 * TSEQ * H3 * 2;        // 6.3 MB
  float* xa   = (float*)p;                  p += (size_t)2 * TSEQ * H * 4;         // 4.2 MB
  float* hseq = (float*)p;                  p += (size_t)2 * TSEQ * H * 4;         // 4.2 MB
  __hip_bfloat16* wg = (__hip_bfloat16*)p;  p += (size_t)2 * TSEQ * KEND * H3 * 2; // 50.3 MB

  hipFuncSetAttribute((const void*)k_scan,
                      hipFuncAttributeMaxDynamicSharedMemorySize, SMEM_SCAN);

  k_embed<<<dim3(TSEQ, 2), 256, 0, stream>>>(
      inputs, E, fw_W_ih, fw_b, fw_aW_ih, fw_ab, bw_W_ih, bw_b, bw_aW_ih, bw_ab, xg, xa);
  k_wordgates<<<dim3(TSEQ, 2), 256, 0, stream>>>(
      fw_ids, fw_mask, bw_ids, bw_mask, word_table, fw_wW_ih, fw_wb, bw_wW_ih, bw_wb, wg);
  k_scan<<<2, NTH, SMEM_SCAN, stream>>>(
      xg, xa, wg, hseq, fw_start, fw_mask, bw_start, bw_mask,
      fw_W_hh, fw_aW_hh, fw_wW_hh, bw_W_hh, bw_aW_hh, bw_wW_hh);
  k_proj<<<TSEQ, 64, 0, stream>>>(hseq, W_lin, b_lin, (float*)d_out);
}

// Round 4
// 21779.692 us; speedup vs baseline: 2.3580x; 2.3580x over previous
//
#include <hip/hip_runtime.h>
#include <hip/hip_bf16.h>

// ---------------------------------------------------------------------------
// Lattice LSTM (bidirectional) — round 3: single-CU-per-direction scan,
// u-ring reformulation + partial weight residency + L2 register streaming.
//
// Key algebra: word gates for word (start s, end t) = wg_pre[t,w] + u[s] where
// u[s] = h[s] @ wW_hh is computed ONCE at step s+1 (shared by all words
// starting at s). Per step the gate matvec is a single row:
//   [v|u](t-1) = h[t-1] @ [W_hh | wW_hh]   (256 x 1536, bf16 MFMA)
// plus the per-word alpha matvec cw @ aW_hh (256 x 256).
//
// Weights packed to MFMA-fragment layout (k_pack). Per direction (112 tiles of
// 16 cols x 256 k): 32 tiles VGPR-resident (4/wave), 8 tiles LDS-resident
// (1/wave), 72 tiles streamed from L2 each step into registers (double-
// buffered half-tiles). No cross-CU sync anywhere; 4 __syncthreads per step.
// ---------------------------------------------------------------------------

#define TSEQ 2048
#define KEND 8
#define DEMB 100
#define H    256
#define H3   768
#define WD   300
#define CCLS 18
#define NTH  512

typedef __attribute__((ext_vector_type(8))) short bf16x8;
typedef __attribute__((ext_vector_type(4))) float f32x4;

// LDS offsets (bytes)
#define LO_LDSW 0        // LDS-resident weight tiles [8][8 ks][64 lanes][16B] 65536
#define LO_U    65536    // u-ring bf16 [8][768]                              12288
#define LO_RC   77824    // ringC f32 [8][256]                                 8192
#define LO_PRE  86016    // preS (v) f32 [768]                                 3072
#define LO_A1   89088    // A1 bf16 [16][256] row0=h, XOR-swizzled             8192
#define LO_A2   97280    // A2 bf16 [16][256] rows=cw words, XOR-swizzled      8192
#define LO_CW   105472   // cwS f32 [8][256]                                   8192
#define LO_AW   113664   // awS f32 [8][256]                                   8192
#define LO_WG   121856   // wgS bf16 [8][768] (per-slot word-gate preacts)    12288
#define LO_MT   134144   // meta int [2][32]: {nw, slot[8], start[8]}           256
#define SMEM_SCAN 134400

__device__ __forceinline__ float sigf(float x) { return 1.0f / (1.0f + expf(-x)); }
__device__ __forceinline__ float bf2f(unsigned short u) { return __uint_as_float(((unsigned)u) << 16); }
__device__ __forceinline__ unsigned short f2bf(float f) {
  union { float f; unsigned u; } x; x.f = f;
  unsigned r = x.u + 0x7fffu + ((x.u >> 16) & 1u);   // RNE
  return (unsigned short)(r >> 16);
}

// ---------------- K0: pack weights into MFMA-fragment layout (bf16) ---------
// Tile T (0..111): T<96 -> gate cols [W_hh|wW_hh] col=T*16+(lane&15);
// T>=96 -> aW_hh col=(T-96)*16+(lane&15). Frag (T,ks): lane holds 8 bf16 for
// k = ks*32 + (lane>>4)*8 + e. 1024 B per frag.
__global__ __launch_bounds__(64) void k_pack(
    const float* __restrict__ W_hh_f, const float* __restrict__ wW_hh_f, const float* __restrict__ aW_hh_f,
    const float* __restrict__ W_hh_b, const float* __restrict__ wW_hh_b, const float* __restrict__ aW_hh_b,
    unsigned short* __restrict__ Wpk)
{
  const int T = blockIdx.x, dir = blockIdx.y;
  const int lane = threadIdx.x;
  const float* Wg = dir ? W_hh_b  : W_hh_f;
  const float* Ww = dir ? wW_hh_b : wW_hh_f;
  const float* Wa = dir ? aW_hh_b : aW_hh_f;
  for (int ks = 0; ks < 8; ++ks) {
    bf16x8 sv;
#pragma unroll
    for (int e = 0; e < 8; ++e) {
      const int k = ks * 32 + (lane >> 4) * 8 + e;
      float f;
      if (T < 96) {
        const int c = T * 16 + (lane & 15);
        f = (c < H3) ? Wg[(size_t)k * H3 + c] : Ww[(size_t)k * H3 + (c - H3)];
      } else {
        const int c = (T - 96) * 16 + (lane & 15);
        f = Wa[(size_t)k * H + c];
      }
      sv[e] = (short)f2bf(f);
    }
    *(bf16x8*)(Wpk + (((size_t)dir * 112 + T) * 8 + ks) * 512 + lane * 8) = sv;
  }
}

// ---------------- K1: char embedding -> gate / alpha input preacts ----------
__global__ __launch_bounds__(256) void k_embed(
    const int* __restrict__ inputs, const float* __restrict__ E,
    const float* __restrict__ W_ih_f, const float* __restrict__ b_f,
    const float* __restrict__ aW_ih_f, const float* __restrict__ ab_f,
    const float* __restrict__ W_ih_b, const float* __restrict__ b_b,
    const float* __restrict__ aW_ih_b, const float* __restrict__ ab_b,
    __hip_bfloat16* __restrict__ xg, float* __restrict__ xa)
{
  const int t = blockIdx.x, dir = blockIdx.y;
  const int tid = threadIdx.x;
  const float* W_ih = dir ? W_ih_b : W_ih_f;
  const float* bb   = dir ? b_b    : b_f;
  const float* aW   = dir ? aW_ih_b : aW_ih_f;
  const float* ab   = dir ? ab_b   : ab_f;
  const int src = dir ? (TSEQ - 1 - t) : t;

  __shared__ float xr[DEMB];
  if (tid < DEMB) xr[tid] = E[(size_t)inputs[src] * DEMB + tid];
  __syncthreads();

  float a0 = bb[tid], a1 = bb[H + tid], a2 = bb[2 * H + tid], a3 = ab[tid];
  for (int r = 0; r < DEMB; r += 4) {
    const float4 e4 = *reinterpret_cast<const float4*>(&xr[r]);
    const float ev[4] = {e4.x, e4.y, e4.z, e4.w};
#pragma unroll
    for (int kk = 0; kk < 4; ++kk) {
      const float* wp = W_ih + (size_t)(r + kk) * H3 + tid;
      a0 += ev[kk] * wp[0];
      a1 += ev[kk] * wp[H];
      a2 += ev[kk] * wp[2 * H];
      a3 += ev[kk] * aW[(size_t)(r + kk) * H + tid];
    }
  }
  __hip_bfloat16* xgrow = xg + ((size_t)dir * TSEQ + t) * H3;
  xgrow[tid]         = __float2bfloat16(a0);
  xgrow[H + tid]     = __float2bfloat16(a1);
  xgrow[2 * H + tid] = __float2bfloat16(a2);
  xa[((size_t)dir * TSEQ + t) * H + tid] = a3;
}

// ---------------- K2: word-gate preacts (valid slots only), bf16 out --------
__global__ __launch_bounds__(256) void k_wordgates(
    const int* __restrict__ fw_ids, const int* __restrict__ fw_mask,
    const int* __restrict__ bw_ids, const int* __restrict__ bw_mask,
    const float* __restrict__ word_table,
    const float* __restrict__ wW_ih_f, const float* __restrict__ wb_f,
    const float* __restrict__ wW_ih_b, const float* __restrict__ wb_b,
    __hip_bfloat16* __restrict__ wg)
{
  const int t = blockIdx.x, dir = blockIdx.y;
  const int tid = threadIdx.x;
  const int* ids = (dir ? bw_ids : fw_ids) + t * KEND;
  const int* msk = (dir ? bw_mask : fw_mask) + t * KEND;
  const float* wW = dir ? wW_ih_b : wW_ih_f;
  const float* wb = dir ? wb_b    : wb_f;

  __shared__ float we[KEND][WD];
  for (int w = 0; w < KEND; ++w) {
    if (msk[w]) {
      const float* src = word_table + (size_t)ids[w] * WD;
      for (int i = tid; i < WD; i += 256) we[w][i] = src[i];
    }
  }
  __syncthreads();

  __hip_bfloat16* out = wg + ((size_t)dir * TSEQ + t) * KEND * H3;
  for (int w = 0; w < KEND; ++w) {
    if (!msk[w]) continue;
    float a0 = wb[tid], a1 = wb[H + tid], a2 = wb[2 * H + tid];
    for (int r = 0; r < WD; r += 4) {
      const float4 e4 = *reinterpret_cast<const float4*>(&we[w][r]);
      const float ev[4] = {e4.x, e4.y, e4.z, e4.w};
#pragma unroll
      for (int kk = 0; kk < 4; ++kk) {
        const float* wp = wW + (size_t)(r + kk) * H3 + tid;
        a0 += ev[kk] * wp[0];
        a1 += ev[kk] * wp[H];
        a2 += ev[kk] * wp[2 * H];
      }
    }
    out[w * H3 + tid]         = __float2bfloat16(a0);
    out[w * H3 + H + tid]     = __float2bfloat16(a1);
    out[w * H3 + 2 * H + tid] = __float2bfloat16(a2);
  }
}

// ---------------- K3: single-CU scan, 1 block per direction -----------------
__global__ __launch_bounds__(NTH, 2) void k_scan(
    const __hip_bfloat16* __restrict__ xg, const float* __restrict__ xa,
    const __hip_bfloat16* __restrict__ wg, float* __restrict__ hseq,
    const int* __restrict__ fw_start, const int* __restrict__ fw_mask,
    const int* __restrict__ bw_start, const int* __restrict__ bw_mask,
    const unsigned short* __restrict__ Wpk)
{
  extern __shared__ char smem[];
  float* ringC = (float*)(smem + LO_RC);
  float* preS  = (float*)(smem + LO_PRE);
  float* cwS   = (float*)(smem + LO_CW);
  float* awS   = (float*)(smem + LO_AW);
  unsigned short* uring = (unsigned short*)(smem + LO_U);
  unsigned short* wgS   = (unsigned short*)(smem + LO_WG);
  int* metaI = (int*)(smem + LO_MT);

  const int tid  = threadIdx.x;
  const int dir  = blockIdx.x;
  const int lane = tid & 63;
  const int wv   = tid >> 6;          // wave 0..7

  const int* startA = dir ? bw_start : fw_start;
  const int* maskA  = dir ? bw_mask  : fw_mask;
  const char* WpkD = (const char*)(Wpk + (size_t)dir * 112 * 8 * 512);

  // ---- one-time: VGPR-resident B fragments (tiles 4wv..4wv+3) --------------
  bf16x8 rW[4][8];
  {
    const char* rp = WpkD + (size_t)(4 * wv) * 8192 + lane * 16;
#pragma unroll
    for (int n = 0; n < 4; ++n)
#pragma unroll
      for (int ks = 0; ks < 8; ++ks)
        rW[n][ks] = *(const bf16x8*)(rp + (n * 8 + ks) * 1024);
  }
  // ---- one-time: LDS-resident tile (32+wv) ---------------------------------
  {
    const char* lp = WpkD + (size_t)(32 + wv) * 8192 + lane * 16;
#pragma unroll
    for (int ks = 0; ks < 8; ++ks) {
      const bf16x8 v = *(const bf16x8*)(lp + ks * 1024);
      *(bf16x8*)(smem + LO_LDSW + wv * 8192 + ks * 1024 + lane * 16) = v;
    }
  }
  // ---- zero A1, A2, ringC --------------------------------------------------
  for (int o = tid * 16; o < 16384; o += NTH * 16)
    *(uint4*)(smem + LO_A1 + o) = uint4{0, 0, 0, 0};
  for (int o = tid * 16; o < 8192; o += NTH * 16)
    *(uint4*)(smem + LO_RC + o) = uint4{0, 0, 0, 0};

  // ---- prefetch t=0 inputs + stage -----------------------------------------
  unsigned short nxI = 0, nxO = 0, nxG = 0; float nxA = 0.f;
  unsigned short cxI = 0, cxO = 0, cxG = 0; float cxA = 0.f;
  uint4 w0 = uint4{0, 0, 0, 0}, w1 = uint4{0, 0, 0, 0};
  int nmt = 0;
  {
    if (tid < H) {
      const unsigned short* xr = (const unsigned short*)(xg + (size_t)dir * TSEQ * H3);
      nxI = xr[tid]; nxO = xr[H + tid]; nxG = xr[2 * H + tid];
      nxA = xa[(size_t)dir * TSEQ * H + tid];
    }
    const char* wgr = (const char*)(wg + (size_t)dir * TSEQ * KEND * H3);
    w0 = *(const uint4*)(wgr + tid * 16);
    if (tid < 256) w1 = *(const uint4*)(wgr + 8192 + tid * 16);
    if (wv == 7) {
      if (lane < 8) nmt = maskA[lane];
      else if (lane < 16) nmt = startA[lane - 8];
    }
  }
  __syncthreads();
  *(uint4*)((char*)wgS + tid * 16) = w0;
  if (tid < 256) *(uint4*)((char*)wgS + 8192 + tid * 16) = w1;
  if (wv == 7) {
    int mAll[8], sAll[8];
#pragma unroll
    for (int s = 0; s < 8; ++s) { mAll[s] = __shfl(nmt, s); sAll[s] = __shfl(nmt, 8 + s); }
    if (lane == 0) {
      int n = 0;
      for (int s = 0; s < 8; ++s)
        if (mAll[s]) { metaI[1 + n] = s; metaI[9 + n] = sAll[s]; ++n; }
      metaI[0] = n;
    }
  }
  cxI = nxI; cxO = nxO; cxG = nxG; cxA = nxA;
  __syncthreads();

  // A-frag LDS read addressing (XOR-swizzled): row=lane&15, base cb=ks*64+(lane>>4)*16
  const int arow = (lane & 15);
  const int asw  = (arow & 7) << 4;
  const int abase = arow * 512 + (((lane >> 4) * 16) ^ asw);   // ks adds ^ at bit>=6 via XOR below

  // ---- main loop -----------------------------------------------------------
  for (int t = 0; t < TSEQ; ++t) {
    const int* mp = metaI + (t & 1) * 32;
    const int nw = mp[0];
    const int uslot = ((t - 1) & 7);

    // ======== S1: gate matvec  [v|u](t-1) = h(t-1) @ [W_hh|wW_hh] ==========
    {
      // stream prefetch: first 8 frags of this wave's 7 streamed gate tiles
      const char* sgp = WpkD + (size_t)(40 + 7 * wv) * 8192 + lane * 16;
      bf16x8 sA0 = *(const bf16x8*)(sgp + 0 * 1024);
      bf16x8 sA1 = *(const bf16x8*)(sgp + 1 * 1024);
      bf16x8 sA2 = *(const bf16x8*)(sgp + 2 * 1024);
      bf16x8 sA3 = *(const bf16x8*)(sgp + 3 * 1024);
      bf16x8 sB0 = *(const bf16x8*)(sgp + 4 * 1024);
      bf16x8 sB1 = *(const bf16x8*)(sgp + 5 * 1024);
      bf16x8 sB2 = *(const bf16x8*)(sgp + 6 * 1024);
      bf16x8 sB3 = *(const bf16x8*)(sgp + 7 * 1024);

      // A-frags (h row 0; rows 1-15 are zero)
      bf16x8 a0, a1, a2, a3, a4, a5, a6, a7;
      {
        const char* ab = smem + LO_A1 + abase;
        a0 = *(const bf16x8*)(ab + (0 * 64));
        a1 = *(const bf16x8*)(ab + (1 * 64));
        a2 = *(const bf16x8*)(ab + (2 * 64));
        a3 = *(const bf16x8*)(ab + (3 * 64));
        a4 = *(const bf16x8*)(ab + (4 * 64));
        a5 = *(const bf16x8*)(ab + (5 * 64));
        a6 = *(const bf16x8*)(ab + (6 * 64));
        a7 = *(const bf16x8*)(ab + (7 * 64));
      }

      // resident tiles (cols 64wv .. 64wv+63, all -> v)
#pragma unroll
      for (int n = 0; n < 4; ++n) {
        f32x4 acc = {0.f, 0.f, 0.f, 0.f};
        acc = __builtin_amdgcn_mfma_f32_16x16x32_bf16(a0, rW[n][0], acc, 0, 0, 0);
        acc = __builtin_amdgcn_mfma_f32_16x16x32_bf16(a1, rW[n][1], acc, 0, 0, 0);
        acc = __builtin_amdgcn_mfma_f32_16x16x32_bf16(a2, rW[n][2], acc, 0, 0, 0);
        acc = __builtin_amdgcn_mfma_f32_16x16x32_bf16(a3, rW[n][3], acc, 0, 0, 0);
        acc = __builtin_amdgcn_mfma_f32_16x16x32_bf16(a4, rW[n][4], acc, 0, 0, 0);
        acc = __builtin_amdgcn_mfma_f32_16x16x32_bf16(a5, rW[n][5], acc, 0, 0, 0);
        acc = __builtin_amdgcn_mfma_f32_16x16x32_bf16(a6, rW[n][6], acc, 0, 0, 0);
        acc = __builtin_amdgcn_mfma_f32_16x16x32_bf16(a7, rW[n][7], acc, 0, 0, 0);
        if (lane < 16) preS[(4 * wv + n) * 16 + lane] = acc[0];
      }
      // LDS-resident tile 32+wv (cols 512+16wv -> v)
      {
        f32x4 acc = {0.f, 0.f, 0.f, 0.f};
        const char* lb = smem + LO_LDSW + wv * 8192 + lane * 16;
        acc = __builtin_amdgcn_mfma_f32_16x16x32_bf16(a0, *(const bf16x8*)(lb + 0 * 1024), acc, 0, 0, 0);
        acc = __builtin_amdgcn_mfma_f32_16x16x32_bf16(a1, *(const bf16x8*)(lb + 1 * 1024), acc, 0, 0, 0);
        acc = __builtin_amdgcn_mfma_f32_16x16x32_bf16(a2, *(const bf16x8*)(lb + 2 * 1024), acc, 0, 0, 0);
        acc = __builtin_amdgcn_mfma_f32_16x16x32_bf16(a3, *(const bf16x8*)(lb + 3 * 1024), acc, 0, 0, 0);
        acc = __builtin_amdgcn_mfma_f32_16x16x32_bf16(a4, *(const bf16x8*)(lb + 4 * 1024), acc, 0, 0, 0);
        acc = __builtin_amdgcn_mfma_f32_16x16x32_bf16(a5, *(const bf16x8*)(lb + 5 * 1024), acc, 0, 0, 0);
        acc = __builtin_amdgcn_mfma_f32_16x16x32_bf16(a6, *(const bf16x8*)(lb + 6 * 1024), acc, 0, 0, 0);
        acc = __builtin_amdgcn_mfma_f32_16x16x32_bf16(a7, *(const bf16x8*)(lb + 7 * 1024), acc, 0, 0, 0);
        if (lane < 16) preS[512 + wv * 16 + lane] = acc[0];
      }
      // streamed tiles 40+7wv .. 46+7wv (double-buffered half-tiles)
#pragma unroll 1
      for (int ti = 0; ti < 7; ++ti) {
        const int fb = ti * 8;
        f32x4 acc = {0.f, 0.f, 0.f, 0.f};
        acc = __builtin_amdgcn_mfma_f32_16x16x32_bf16(a0, sA0, acc, 0, 0, 0);
        acc = __builtin_amdgcn_mfma_f32_16x16x32_bf16(a1, sA1, acc, 0, 0, 0);
        acc = __builtin_amdgcn_mfma_f32_16x16x32_bf16(a2, sA2, acc, 0, 0, 0);
        acc = __builtin_amdgcn_mfma_f32_16x16x32_bf16(a3, sA3, acc, 0, 0, 0);
        if (ti < 6) {
          sA0 = *(const bf16x8*)(sgp + (size_t)(fb + 8)  * 1024);
          sA1 = *(const bf16x8*)(sgp + (size_t)(fb + 9)  * 1024);
          sA2 = *(const bf16x8*)(sgp + (size_t)(fb + 10) * 1024);
          sA3 = *(const bf16x8*)(sgp + (size_t)(fb + 11) * 1024);
        }
        acc = __builtin_amdgcn_mfma_f32_16x16x32_bf16(a4, sB0, acc, 0, 0, 0);
        acc = __builtin_amdgcn_mfma_f32_16x16x32_bf16(a5, sB1, acc, 0, 0, 0);
        acc = __builtin_amdgcn_mfma_f32_16x16x32_bf16(a6, sB2, acc, 0, 0, 0);
        acc = __builtin_amdgcn_mfma_f32_16x16x32_bf16(a7, sB3, acc, 0, 0, 0);
        if (ti < 6) {
          sB0 = *(const bf16x8*)(sgp + (size_t)(fb + 12) * 1024);
          sB1 = *(const bf16x8*)(sgp + (size_t)(fb + 13) * 1024);
          sB2 = *(const bf16x8*)(sgp + (size_t)(fb + 14) * 1024);
          sB3 = *(const bf16x8*)(sgp + (size_t)(fb + 15) * 1024);
        }
        const int Tg = 40 + 7 * wv + ti;
        if (lane < 16) {
          if (Tg < 48) preS[Tg * 16 + lane] = acc[0];
          else uring[uslot * 768 + (Tg - 48) * 16 + lane] = f2bf(acc[0]);
        }
      }
    }
    __syncthreads();   // sync1: preS + u(t-1) ready

    // ======== S2: input prefetch (t+1) + word cells =========================
    {
      const int tn = (t + 1 < TSEQ) ? t + 1 : TSEQ - 1;
      if (tid < H) {
        const unsigned short* xr = (const unsigned short*)(xg + ((size_t)dir * TSEQ + tn) * H3);
        nxI = xr[tid]; nxO = xr[H + tid]; nxG = xr[2 * H + tid];
        nxA = xa[((size_t)dir * TSEQ + tn) * H + tid];
      }
      const char* wgr = (const char*)(wg + ((size_t)dir * TSEQ + tn) * KEND * H3);
      w0 = *(const uint4*)(wgr + tid * 16);
      if (tid < 256) w1 = *(const uint4*)(wgr + 8192 + tid * 16);
      if (wv == 7) {
        if (lane < 8) nmt = maskA[tn * KEND + lane];
        else if (lane < 16) nmt = startA[tn * KEND + (lane - 8)];
      }
    }
    for (int u0 = tid; u0 < nw * 256; u0 += NTH) {
      const int w = u0 >> 8, j = u0 & 255;
      const int slot = mp[1 + w];
      const int ss = mp[9 + w] & 7;
      const float wi  = bf2f(wgS[slot * 768 + j])       + bf2f(uring[ss * 768 + j]);
      const float wf  = bf2f(wgS[slot * 768 + 256 + j]) + bf2f(uring[ss * 768 + 256 + j]);
      const float wgg = bf2f(wgS[slot * 768 + 512 + j]) + bf2f(uring[ss * 768 + 512 + j]);
      const float cs  = ringC[ss * 256 + j];
      const float cv  = sigf(wf) * cs + sigf(wi) * tanhf(wgg);
      cwS[w * 256 + j] = cv;
      // A2 row w, col j, XOR-swizzled
      *(unsigned short*)(smem + LO_A2 + w * 512 + ((j * 2) ^ ((w & 7) << 4))) = f2bf(cv);
    }
    __syncthreads();   // sync2: A2/cwS ready

    // ======== S3: alpha matvec  aw = cw @ aW_hh  (2 streamed tiles/wave) ====
    {
      const char* sap = WpkD + (size_t)(96 + 2 * wv) * 8192 + lane * 16;
      bf16x8 sA0 = *(const bf16x8*)(sap + 0 * 1024);
      bf16x8 sA1 = *(const bf16x8*)(sap + 1 * 1024);
      bf16x8 sA2 = *(const bf16x8*)(sap + 2 * 1024);
      bf16x8 sA3 = *(const bf16x8*)(sap + 3 * 1024);
      bf16x8 sB0 = *(const bf16x8*)(sap + 4 * 1024);
      bf16x8 sB1 = *(const bf16x8*)(sap + 5 * 1024);
      bf16x8 sB2 = *(const bf16x8*)(sap + 6 * 1024);
      bf16x8 sB3 = *(const bf16x8*)(sap + 7 * 1024);
      bf16x8 a0, a1, a2, a3, a4, a5, a6, a7;
      {
        const char* ab = smem + LO_A2 + abase;
        a0 = *(const bf16x8*)(ab + (0 * 64));
        a1 = *(const bf16x8*)(ab + (1 * 64));
        a2 = *(const bf16x8*)(ab + (2 * 64));
        a3 = *(const bf16x8*)(ab + (3 * 64));
        a4 = *(const bf16x8*)(ab + (4 * 64));
        a5 = *(const bf16x8*)(ab + (5 * 64));
        a6 = *(const bf16x8*)(ab + (6 * 64));
        a7 = *(const bf16x8*)(ab + (7 * 64));
      }
      f32x4 acc = {0.f, 0.f, 0.f, 0.f};
      acc = __builtin_amdgcn_mfma_f32_16x16x32_bf16(a0, sA0, acc, 0, 0, 0);
      acc = __builtin_amdgcn_mfma_f32_16x16x32_bf16(a1, sA1, acc, 0, 0, 0);
      acc = __builtin_amdgcn_mfma_f32_16x16x32_bf16(a2, sA2, acc, 0, 0, 0);
      acc = __builtin_amdgcn_mfma_f32_16x16x32_bf16(a3, sA3, acc, 0, 0, 0);
      sA0 = *(const bf16x8*)(sap + 8  * 1024);
      sA1 = *(const bf16x8*)(sap + 9  * 1024);
      sA2 = *(const bf16x8*)(sap + 10 * 1024);
      sA3 = *(const bf16x8*)(sap + 11 * 1024);
      acc = __builtin_amdgcn_mfma_f32_16x16x32_bf16(a4, sB0, acc, 0, 0, 0);
      acc = __builtin_amdgcn_mfma_f32_16x16x32_bf16(a5, sB1, acc, 0, 0, 0);
      acc = __builtin_amdgcn_mfma_f32_16x16x32_bf16(a6, sB2, acc, 0, 0, 0);
      acc = __builtin_amdgcn_mfma_f32_16x16x32_bf16(a7, sB3, acc, 0, 0, 0);
      sB0 = *(const bf16x8*)(sap + 12 * 1024);
      sB1 = *(const bf16x8*)(sap + 13 * 1024);
      sB2 = *(const bf16x8*)(sap + 14 * 1024);
      sB3 = *(const bf16x8*)(sap + 15 * 1024);
      {
        const int colA = (2 * wv) * 16 + (lane & 15);
#pragma unroll
        for (int r = 0; r < 4; ++r) {
          const int row = (lane >> 4) * 4 + r;
          if (row < nw) awS[row * 256 + colA] = acc[r];
        }
      }
      acc = f32x4{0.f, 0.f, 0.f, 0.f};
      acc = __builtin_amdgcn_mfma_f32_16x16x32_bf16(a0, sA0, acc, 0, 0, 0);
      acc = __builtin_amdgcn_mfma_f32_16x16x32_bf16(a1, sA1, acc, 0, 0, 0);
      acc = __builtin_amdgcn_mfma_f32_16x16x32_bf16(a2, sA2, acc, 0, 0, 0);
      acc = __builtin_amdgcn_mfma_f32_16x16x32_bf16(a3, sA3, acc, 0, 0, 0);
      acc = __builtin_amdgcn_mfma_f32_16x16x32_bf16(a4, sB0, acc, 0, 0, 0);
      acc = __builtin_amdgcn_mfma_f32_16x16x32_bf16(a5, sB1, acc, 0, 0, 0);
      acc = __builtin_amdgcn_mfma_f32_16x16x32_bf16(a6, sB2, acc, 0, 0, 0);
      acc = __builtin_amdgcn_mfma_f32_16x16x32_bf16(a7, sB3, acc, 0, 0, 0);
      {
        const int colA = (2 * wv + 1) * 16 + (lane & 15);
#pragma unroll
        for (int r = 0; r < 4; ++r) {
          const int row = (lane >> 4) * 4 + r;
          if (row < nw) awS[row * 256 + colA] = acc[r];
        }
      }
    }
    __syncthreads();   // sync3: awS ready

    // ======== S4: merge + state update + staging ============================
    if (tid < H) {
      const int j = tid;
      const float i_s = sigf(bf2f(cxI) + preS[j]);
      const float o_s = sigf(bf2f(cxO) + preS[256 + j]);
      const float g_t = tanhf(bf2f(cxG) + preS[512 + j]);
      float cnew;
      if (nw > 0) {
        const float e_i = expf(i_s);
        float num = e_i * g_t, den = e_i;
        for (int w = 0; w < nw; ++w) {
          const float a  = sigf(cxA + awS[w * 256 + j]);
          const float ea = expf(a);
          num += ea * cwS[w * 256 + j];
          den += ea;
        }
        cnew = num / den;
      } else {
        cnew = (1.f - i_s) * ringC[((t - 1) & 7) * 256 + j] + i_s * g_t;
      }
      const float hnew = o_s * tanhf(cnew);
      ringC[(t & 7) * 256 + j] = cnew;
      ((unsigned short*)(smem + LO_A1))[j] = f2bf(hnew);   // A1 row 0 (swizzle=0)
      hseq[((size_t)dir * TSEQ + t) * H + j] = hnew;
    }
    *(uint4*)((char*)wgS + tid * 16) = w0;
    if (tid < 256) *(uint4*)((char*)wgS + 8192 + tid * 16) = w1;
    if (wv == 7) {
      int mAll[8], sAll[8];
#pragma unroll
      for (int s = 0; s < 8; ++s) { mAll[s] = __shfl(nmt, s); sAll[s] = __shfl(nmt, 8 + s); }
      if (lane == 0) {
        int* mq = metaI + ((t + 1) & 1) * 32;
        int n = 0;
        for (int s = 0; s < 8; ++s)
          if (mAll[s]) { mq[1 + n] = s; mq[9 + n] = sAll[s]; ++n; }
        mq[0] = n;
      }
    }
    cxI = nxI; cxO = nxO; cxG = nxG; cxA = nxA;
    __syncthreads();   // sync4: A1/ringC/wgS/meta ready for t+1
  }
}

// ---------------- K4: output projection -------------------------------------
__global__ __launch_bounds__(64) void k_proj(
    const float* __restrict__ hseq, const float* __restrict__ W_lin,
    const float* __restrict__ b_lin, float* __restrict__ out)
{
  const int t = blockIdx.x;
  const int tid = threadIdx.x;
  __shared__ float hrow[2 * H];
  for (int i = tid; i < H; i += 64) {
    hrow[i]     = hseq[(size_t)t * H + i];
    hrow[H + i] = hseq[((size_t)TSEQ + (TSEQ - 1 - t)) * H + i];
  }
  __syncthreads();
  if (tid < CCLS) {
    float acc = b_lin[tid];
    for (int j = 0; j < 2 * H; ++j) acc += hrow[j] * W_lin[(size_t)j * CCLS + tid];
    out[(size_t)t * CCLS + tid] = acc;
  }
}

// ---------------------------------------------------------------------------
extern "C" void kernel_launch(void* const* d_in, const int* in_sizes, int n_in,
                              void* d_out, int out_size, void* d_ws, size_t ws_size,
                              hipStream_t stream)
{
  const int* inputs   = (const int*)d_in[0];
  const int* fw_ids   = (const int*)d_in[1];
  const int* fw_start = (const int*)d_in[2];
  const int* fw_mask  = (const int*)d_in[3];
  const int* bw_ids   = (const int*)d_in[4];
  const int* bw_start = (const int*)d_in[5];
  const int* bw_mask  = (const int*)d_in[6];
  const float* E          = (const float*)d_in[8];
  const float* word_table = (const float*)d_in[9];
  const float* W_lin      = (const float*)d_in[10];
  const float* b_lin      = (const float*)d_in[11];
  const float* fw_W_ih  = (const float*)d_in[12];
  const float* fw_W_hh  = (const float*)d_in[13];
  const float* fw_b     = (const float*)d_in[14];
  const float* fw_aW_ih = (const float*)d_in[15];
  const float* fw_aW_hh = (const float*)d_in[16];
  const float* fw_ab    = (const float*)d_in[17];
  const float* fw_wW_ih = (const float*)d_in[18];
  const float* fw_wW_hh = (const float*)d_in[19];
  const float* fw_wb    = (const float*)d_in[20];
  const float* bw_W_ih  = (const float*)d_in[21];
  const float* bw_W_hh  = (const float*)d_in[22];
  const float* bw_b     = (const float*)d_in[23];
  const float* bw_aW_ih = (const float*)d_in[24];
  const float* bw_aW_hh = (const float*)d_in[25];
  const float* bw_ab    = (const float*)d_in[26];
  const float* bw_wW_ih = (const float*)d_in[27];
  const float* bw_wW_hh = (const float*)d_in[28];
  const float* bw_wb    = (const float*)d_in[29];

  char* p = (char*)d_ws;
  __hip_bfloat16* xg = (__hip_bfloat16*)p;  p += (size_t)2 * TSEQ * H3 * 2;        // 6.3 MB
  float* xa   = (float*)p;                  p += (size_t)2 * TSEQ * H * 4;         // 4.2 MB
  float* hseq = (float*)p;                  p += (size_t)2 * TSEQ * H * 4;         // 4.2 MB
  __hip_bfloat16* wg = (__hip_bfloat16*)p;  p += (size_t)2 * TSEQ * KEND * H3 * 2; // 50.3 MB
  unsigned short* Wpk = (unsigned short*)p; p += (size_t)2 * 112 * 8 * 512 * 2;    // 1.8 MB

  hipFuncSetAttribute((const void*)k_scan,
                      hipFuncAttributeMaxDynamicSharedMemorySize, SMEM_SCAN);

  k_pack<<<dim3(112, 2), 64, 0, stream>>>(
      fw_W_hh, fw_wW_hh, fw_aW_hh, bw_W_hh, bw_wW_hh, bw_aW_hh, Wpk);
  k_embed<<<dim3(TSEQ, 2), 256, 0, stream>>>(
      inputs, E, fw_W_ih, fw_b, fw_aW_ih, fw_ab, bw_W_ih, bw_b, bw_aW_ih, bw_ab, xg, xa);
  k_wordgates<<<dim3(TSEQ, 2), 256, 0, stream>>>(
      fw_ids, fw_mask, bw_ids, bw_mask, word_table, fw_wW_ih, fw_wb, bw_wW_ih, bw_wb, wg);
  k_scan<<<2, NTH, SMEM_SCAN, stream>>>(
      xg, xa, wg, hseq, fw_start, fw_mask, bw_start, bw_mask, Wpk);
  k_proj<<<TSEQ, 64, 0, stream>>>(hseq, W_lin, b_lin, (float*)d_out);
}

// Round 5
// 21196.402 us; speedup vs baseline: 2.4229x; 1.0275x over previous
//
#include <hip/hip_runtime.h>
#include <hip/hip_bf16.h>

// ---------------------------------------------------------------------------
// Lattice LSTM (bidirectional) — round 4: 2 CUs per direction, fully resident
// weights, one agent-scope atomic exchange (1.5 KB each way) per step.
//
//   Per direction: CU side0 owns v = h@W_hh (48 tiles, VGPR-resident),
//   CU side1 owns u = h@wW_hh (48 tiles, VGPR-resident). aW_hh (16 tiles)
//   duplicated in LDS on both. Word cells / alpha / merge run redundantly on
//   both CUs from bit-identical inputs (v rounded through bf16 on both sides).
//   Exchange: payload = 768 bf16 via relaxed agent-scope atomics (bypass
//   non-coherent per-XCD L2), monotonic flag after __syncthreads (vmcnt drain).
// ---------------------------------------------------------------------------

#define TSEQ 2048
#define KEND 8
#define DEMB 100
#define H    256
#define H3   768
#define WD   300
#define CCLS 18
#define NTH  512

typedef __attribute__((ext_vector_type(8))) short bf16x8;
typedef __attribute__((ext_vector_type(4))) float f32x4;

// LDS offsets (bytes)
#define LO_AT  0        // alpha weight tiles [16][8 ks][64 lanes][16B]  131072
#define LO_A1  131072   // h(t-1) row bf16[256]                             512
#define LO_A2  131584   // cw rows bf16 [8][264] (528B stride)             4224
#define LO_UR  135808   // u-ring bf16 [7][768]                           10752
#define LO_RC  146560   // ringC f32 [8][256]                              8192
#define LO_PRE 154752   // preS (v) f32 [768]                              3072
#define LO_AWS 157824   // awS bf16 [8][256]                               4096
#define LO_MT  161920   // meta int [2][32]: {nw, slot[8], start[8]}        256
#define SMEM_SCAN 162176

__device__ __forceinline__ float sigf(float x) { return 1.0f / (1.0f + expf(-x)); }
__device__ __forceinline__ float bf2f(unsigned u) { return __uint_as_float(u << 16); }
__device__ __forceinline__ unsigned f2bf(float f) {
  union { float f; unsigned u; } x; x.f = f;
  unsigned r = x.u + 0x7fffu + ((x.u >> 16) & 1u);   // RNE
  return r >> 16;
}

// ---------------- K0: pack weights into MFMA-fragment layout (bf16) ---------
// Tile T (0..111): T<96 -> gate cols [W_hh|wW_hh] col=T*16+(lane&15);
// T>=96 -> aW_hh col=(T-96)*16+(lane&15). Frag (T,ks): lane holds 8 bf16 for
// k = ks*32 + (lane>>4)*8 + e. 1024 B per frag.
__global__ __launch_bounds__(64) void k_pack(
    const float* __restrict__ W_hh_f, const float* __restrict__ wW_hh_f, const float* __restrict__ aW_hh_f,
    const float* __restrict__ W_hh_b, const float* __restrict__ wW_hh_b, const float* __restrict__ aW_hh_b,
    unsigned short* __restrict__ Wpk)
{
  const int T = blockIdx.x, dir = blockIdx.y;
  const int lane = threadIdx.x;
  const float* Wg = dir ? W_hh_b  : W_hh_f;
  const float* Ww = dir ? wW_hh_b : wW_hh_f;
  const float* Wa = dir ? aW_hh_b : aW_hh_f;
  for (int ks = 0; ks < 8; ++ks) {
    bf16x8 sv;
#pragma unroll
    for (int e = 0; e < 8; ++e) {
      const int k = ks * 32 + (lane >> 4) * 8 + e;
      float f;
      if (T < 96) {
        const int c = T * 16 + (lane & 15);
        f = (c < H3) ? Wg[(size_t)k * H3 + c] : Ww[(size_t)k * H3 + (c - H3)];
      } else {
        const int c = (T - 96) * 16 + (lane & 15);
        f = Wa[(size_t)k * H + c];
      }
      sv[e] = (short)f2bf(f);
    }
    *(bf16x8*)(Wpk + (((size_t)dir * 112 + T) * 8 + ks) * 512 + lane * 8) = sv;
  }
}

// ---------------- K1: char embedding -> gate / alpha input preacts ----------
__global__ __launch_bounds__(256) void k_embed(
    const int* __restrict__ inputs, const float* __restrict__ E,
    const float* __restrict__ W_ih_f, const float* __restrict__ b_f,
    const float* __restrict__ aW_ih_f, const float* __restrict__ ab_f,
    const float* __restrict__ W_ih_b, const float* __restrict__ b_b,
    const float* __restrict__ aW_ih_b, const float* __restrict__ ab_b,
    __hip_bfloat16* __restrict__ xg, float* __restrict__ xa)
{
  const int t = blockIdx.x, dir = blockIdx.y;
  const int tid = threadIdx.x;
  const float* W_ih = dir ? W_ih_b : W_ih_f;
  const float* bb   = dir ? b_b    : b_f;
  const float* aW   = dir ? aW_ih_b : aW_ih_f;
  const float* ab   = dir ? ab_b   : ab_f;
  const int src = dir ? (TSEQ - 1 - t) : t;

  __shared__ float xr[DEMB];
  if (tid < DEMB) xr[tid] = E[(size_t)inputs[src] * DEMB + tid];
  __syncthreads();

  float a0 = bb[tid], a1 = bb[H + tid], a2 = bb[2 * H + tid], a3 = ab[tid];
  for (int r = 0; r < DEMB; r += 4) {
    const float4 e4 = *reinterpret_cast<const float4*>(&xr[r]);
    const float ev[4] = {e4.x, e4.y, e4.z, e4.w};
#pragma unroll
    for (int kk = 0; kk < 4; ++kk) {
      const float* wp = W_ih + (size_t)(r + kk) * H3 + tid;
      a0 += ev[kk] * wp[0];
      a1 += ev[kk] * wp[H];
      a2 += ev[kk] * wp[2 * H];
      a3 += ev[kk] * aW[(size_t)(r + kk) * H + tid];
    }
  }
  __hip_bfloat16* xgrow = xg + ((size_t)dir * TSEQ + t) * H3;
  xgrow[tid]         = __float2bfloat16(a0);
  xgrow[H + tid]     = __float2bfloat16(a1);
  xgrow[2 * H + tid] = __float2bfloat16(a2);
  xa[((size_t)dir * TSEQ + t) * H + tid] = a3;
}

// ---------------- K2: word-gate preacts (valid slots only), bf16 out --------
__global__ __launch_bounds__(256) void k_wordgates(
    const int* __restrict__ fw_ids, const int* __restrict__ fw_mask,
    const int* __restrict__ bw_ids, const int* __restrict__ bw_mask,
    const float* __restrict__ word_table,
    const float* __restrict__ wW_ih_f, const float* __restrict__ wb_f,
    const float* __restrict__ wW_ih_b, const float* __restrict__ wb_b,
    __hip_bfloat16* __restrict__ wg)
{
  const int t = blockIdx.x, dir = blockIdx.y;
  const int tid = threadIdx.x;
  const int* ids = (dir ? bw_ids : fw_ids) + t * KEND;
  const int* msk = (dir ? bw_mask : fw_mask) + t * KEND;
  const float* wW = dir ? wW_ih_b : wW_ih_f;
  const float* wb = dir ? wb_b    : wb_f;

  __shared__ float we[KEND][WD];
  for (int w = 0; w < KEND; ++w) {
    if (msk[w]) {
      const float* src = word_table + (size_t)ids[w] * WD;
      for (int i = tid; i < WD; i += 256) we[w][i] = src[i];
    }
  }
  __syncthreads();

  __hip_bfloat16* out = wg + ((size_t)dir * TSEQ + t) * KEND * H3;
  for (int w = 0; w < KEND; ++w) {
    if (!msk[w]) continue;
    float a0 = wb[tid], a1 = wb[H + tid], a2 = wb[2 * H + tid];
    for (int r = 0; r < WD; r += 4) {
      const float4 e4 = *reinterpret_cast<const float4*>(&we[w][r]);
      const float ev[4] = {e4.x, e4.y, e4.z, e4.w};
#pragma unroll
      for (int kk = 0; kk < 4; ++kk) {
        const float* wp = wW + (size_t)(r + kk) * H3 + tid;
        a0 += ev[kk] * wp[0];
        a1 += ev[kk] * wp[H];
        a2 += ev[kk] * wp[2 * H];
      }
    }
    out[w * H3 + tid]         = __float2bfloat16(a0);
    out[w * H3 + H + tid]     = __float2bfloat16(a1);
    out[w * H3 + 2 * H + tid] = __float2bfloat16(a2);
  }
}

// ---------------- K3: scan, 4 blocks = dir x side ---------------------------
__global__ __launch_bounds__(NTH, 2) void k_scan(
    const __hip_bfloat16* __restrict__ xg, const float* __restrict__ xa,
    const __hip_bfloat16* __restrict__ wgG, float* __restrict__ hseq,
    const int* __restrict__ fw_start, const int* __restrict__ fw_mask,
    const int* __restrict__ bw_start, const int* __restrict__ bw_mask,
    const unsigned short* __restrict__ Wpk,
    unsigned short* __restrict__ xb, unsigned* __restrict__ xf)
{
  extern __shared__ char smem[];
  float* ringC = (float*)(smem + LO_RC);
  float* preSf = (float*)(smem + LO_PRE);
  int*   metaI = (int*)(smem + LO_MT);

  const int tid  = threadIdx.x;
  const int dir  = blockIdx.x >> 1;
  const int side = blockIdx.x & 1;
  const int lane = tid & 63;
  const int wv   = tid >> 6;          // wave 0..7
  const int lmod = lane & 15;
  const int lgrp = lane >> 4;

  const int* startA = dir ? bw_start : fw_start;
  const int* maskA  = dir ? bw_mask  : fw_mask;
  const char* WpkD = (const char*)(Wpk + (size_t)dir * 112 * 8 * 512);

  // exchange pointers
  unsigned* myPayU = (unsigned*)(xb + (size_t)((dir * 2 + side) * 2) * 768);
  const unsigned long long* peerPayQ =
      (const unsigned long long*)(xb + (size_t)((dir * 2 + (side ^ 1)) * 2) * 768);
  unsigned* myFlag   = xf + (dir * 2 + side) * 32;
  unsigned* peerFlag = xf + (dir * 2 + (side ^ 1)) * 32;

  // ---- one-time: 48 VGPR-resident gate tiles (6/wave) ----------------------
  bf16x8 rW[6][8];
  {
    const char* rp = WpkD + (size_t)(side * 48 + wv * 6) * 8192 + lane * 16;
#pragma unroll
    for (int n = 0; n < 6; ++n)
#pragma unroll
      for (int ks = 0; ks < 8; ++ks)
        rW[n][ks] = *(const bf16x8*)(rp + (n * 8 + ks) * 1024);
  }
  // ---- one-time: 16 alpha tiles -> LDS ------------------------------------
  for (int o = tid * 16; o < 131072; o += NTH * 16)
    *(uint4*)(smem + LO_AT + o) = *(const uint4*)(WpkD + (size_t)96 * 8192 + o);
  // zero A1 + ringC
  if (tid < 32) *(uint4*)(smem + LO_A1 + tid * 16) = uint4{0, 0, 0, 0};
  *(uint4*)(smem + LO_RC + tid * 16) = uint4{0, 0, 0, 0};

  // ---- prologue: prefetch t=0, compact meta[0] -----------------------------
  unsigned nxI = 0, nxO = 0, nxG = 0; float nxA = 0.f;
  unsigned cxI = 0, cxO = 0, cxG = 0; float cxA = 0.f;
  int nmt = 0;
  {
    if (tid < H) {
      const unsigned short* xr = (const unsigned short*)(xg + (size_t)dir * TSEQ * H3);
      nxI = xr[tid]; nxO = xr[H + tid]; nxG = xr[2 * H + tid];
      nxA = xa[(size_t)dir * TSEQ * H + tid];
    }
    if (wv == 7) {
      if (lane < 8) nmt = maskA[lane];
      else if (lane < 16) nmt = startA[lane - 8];
    }
  }
  __syncthreads();
  if (wv == 7) {
    int mAll[8], sAll[8];
#pragma unroll
    for (int s = 0; s < 8; ++s) { mAll[s] = __shfl(nmt, s); sAll[s] = __shfl(nmt, 8 + s); }
    if (lane == 0) {
      int n = 0;
      for (int s = 0; s < 8; ++s)
        if (mAll[s]) { metaI[1 + n] = s; metaI[9 + n] = sAll[s]; ++n; }
      metaI[0] = n;
    }
  }
  cxI = nxI; cxO = nxO; cxG = nxG; cxA = nxA;
  __syncthreads();

  // ---- main loop -----------------------------------------------------------
  for (int t = 0; t < TSEQ; ++t) {
    const int par = t & 1;
    const int* mp = metaI + par * 32;
    const int nw = mp[0];
    const int us7 = (t + 6) % 7;          // u-ring slot for s = t-1

    // -- top of step: issue wg(t) loads for this step's word cells (regs) ----
    unsigned short wgv[12];
#pragma unroll
    for (int it = 0; it < 4; ++it) {
      const int u0 = tid + it * NTH;
      if (u0 < nw * 256) {
        const int w = u0 >> 8, j = u0 & 255;
        const int slot = mp[1 + w];
        const unsigned short* wgp =
            (const unsigned short*)wgG + ((size_t)(dir * TSEQ + t) * KEND + slot) * H3 + j;
        wgv[it * 3 + 0] = wgp[0];
        wgv[it * 3 + 1] = wgp[256];
        wgv[it * 3 + 2] = wgp[512];
      }
    }

    // ======== S1: own half of [v|u] = h(t-1) @ W, publish ===================
    {
      f32x4 acc[6];
#pragma unroll
      for (int n = 0; n < 6; ++n) acc[n] = f32x4{0.f, 0.f, 0.f, 0.f};
#pragma unroll
      for (int ks = 0; ks < 8; ++ks) {
        // broadcast read of A row 0 (rows 1-15 feed only unconsumed D rows)
        const bf16x8 av = *(const bf16x8*)(smem + LO_A1 + ks * 64 + lgrp * 16);
#pragma unroll
        for (int n = 0; n < 6; ++n)
          acc[n] = __builtin_amdgcn_mfma_f32_16x16x32_bf16(av, rW[n][ks], acc[n], 0, 0, 0);
      }
      if (lane < 16) {
#pragma unroll
        for (int n = 0; n < 6; ++n) {
          const int cown = (wv * 6 + n) * 16 + lane;        // 0..767 own col
          const unsigned hb = f2bf(acc[n][0]);
          if (side == 0) preSf[cown] = bf2f(hb);            // force wire rounding
          else ((unsigned short*)(smem + LO_UR))[us7 * 768 + cown] = (unsigned short)hb;
          const unsigned ob = (unsigned)__shfl_xor((int)hb, 1) & 0xffffu;
          if ((lane & 1) == 0) {
            const unsigned word = (hb & 0xffffu) | (ob << 16);
            __hip_atomic_store(myPayU + par * 384 + (cown >> 1), word,
                               __ATOMIC_RELAXED, __HIP_MEMORY_SCOPE_AGENT);
          }
        }
      }
    }
    __syncthreads();   // bar1: all waves' payload stores drained (vmcnt 0)

    if (tid == 0) {
      __hip_atomic_store(myFlag, (unsigned)(t + 1), __ATOMIC_RELAXED, __HIP_MEMORY_SCOPE_AGENT);
      while (__hip_atomic_load(peerFlag, __ATOMIC_RELAXED, __HIP_MEMORY_SCOPE_AGENT) < (unsigned)(t + 1))
        __builtin_amdgcn_s_sleep(2);
    }
    __syncthreads();   // bar2: peer payload published

    if (tid < 192) {
      const unsigned long long q =
          __hip_atomic_load(peerPayQ + par * 192 + tid, __ATOMIC_RELAXED, __HIP_MEMORY_SCOPE_AGENT);
      const int c0 = tid * 4;
      if (side == 0) {
        *(unsigned long long*)(smem + LO_UR + us7 * 1536 + c0 * 2) = q;   // peer u (bf16)
      } else {
        float4 f;
        f.x = bf2f((unsigned)(q & 0xffffu));
        f.y = bf2f((unsigned)((q >> 16) & 0xffffu));
        f.z = bf2f((unsigned)((q >> 32) & 0xffffu));
        f.w = bf2f((unsigned)(q >> 48));
        *(float4*)(smem + LO_PRE + c0 * 4) = f;                           // peer v
      }
    }
    __syncthreads();   // bar3: preS + u(t-1) complete on both sides

    // ======== S2: word cells + prefetch t+1 inputs ==========================
    {
      const int tn = (t + 1 < TSEQ) ? t + 1 : TSEQ - 1;
      if (tid < H) {
        const unsigned short* xr = (const unsigned short*)(xg + ((size_t)dir * TSEQ + tn) * H3);
        nxI = xr[tid]; nxO = xr[H + tid]; nxG = xr[2 * H + tid];
        nxA = xa[((size_t)dir * TSEQ + tn) * H + tid];
      }
      if (wv == 7) {
        if (lane < 8) nmt = maskA[tn * KEND + lane];
        else if (lane < 16) nmt = startA[tn * KEND + (lane - 8)];
      }
    }
#pragma unroll
    for (int it = 0; it < 4; ++it) {
      const int u0 = tid + it * NTH;
      if (u0 < nw * 256) {
        const int w = u0 >> 8, j = u0 & 255;
        const int s = mp[9 + w];
        const int ss7 = s % 7, ss8 = s & 7;
        const unsigned short* ur = (const unsigned short*)(smem + LO_UR) + ss7 * 768;
        const float wi  = bf2f(wgv[it * 3 + 0]) + bf2f(ur[j]);
        const float wf  = bf2f(wgv[it * 3 + 1]) + bf2f(ur[256 + j]);
        const float wgg = bf2f(wgv[it * 3 + 2]) + bf2f(ur[512 + j]);
        const float cs  = ringC[ss8 * 256 + j];
        const float cv  = sigf(wf) * cs + sigf(wi) * tanhf(wgg);
        *(unsigned short*)(smem + LO_A2 + w * 528 + j * 2) = (unsigned short)f2bf(cv);
      }
    }
    __syncthreads();   // bar4: A2 (cw) ready

    // ======== S3: alpha matvec aw = cw @ aW_hh (2 LDS tiles/wave) ===========
    if (nw > 0) {
      const int r2 = (lmod > 7) ? 7 : lmod;    // rows >= 8 unconsumed
      f32x4 ac0 = {0.f, 0.f, 0.f, 0.f}, ac1 = {0.f, 0.f, 0.f, 0.f};
#pragma unroll
      for (int ks = 0; ks < 8; ++ks) {
        const bf16x8 a2v = *(const bf16x8*)(smem + LO_A2 + r2 * 528 + ks * 64 + lgrp * 16);
        const bf16x8 b0 = *(const bf16x8*)(smem + LO_AT + (2 * wv) * 8192 + ks * 1024 + lane * 16);
        const bf16x8 b1 = *(const bf16x8*)(smem + LO_AT + (2 * wv + 1) * 8192 + ks * 1024 + lane * 16);
        ac0 = __builtin_amdgcn_mfma_f32_16x16x32_bf16(a2v, b0, ac0, 0, 0, 0);
        ac1 = __builtin_amdgcn_mfma_f32_16x16x32_bf16(a2v, b1, ac1, 0, 0, 0);
      }
      unsigned short* awS = (unsigned short*)(smem + LO_AWS);
#pragma unroll
      for (int r = 0; r < 4; ++r) {
        const int row = lgrp * 4 + r;
        if (row < nw) {
          awS[row * 256 + (2 * wv) * 16 + lmod]     = (unsigned short)f2bf(ac0[r]);
          awS[row * 256 + (2 * wv + 1) * 16 + lmod] = (unsigned short)f2bf(ac1[r]);
        }
      }
    }
    __syncthreads();   // bar5: awS ready

    // ======== S4: merge + state update (redundant, bit-identical) ===========
    if (tid < H) {
      const int j = tid;
      const float i_s = sigf(bf2f(cxI) + preSf[j]);
      const float o_s = sigf(bf2f(cxO) + preSf[256 + j]);
      const float g_t = tanhf(bf2f(cxG) + preSf[512 + j]);
      float cnew;
      if (nw > 0) {
        const unsigned short* awS = (const unsigned short*)(smem + LO_AWS);
        const float e_i = expf(i_s);
        float num = e_i * g_t, den = e_i;
        for (int w = 0; w < nw; ++w) {
          const float a  = sigf(cxA + bf2f(awS[w * 256 + j]));
          const float ea = expf(a);
          num += ea * bf2f(*(const unsigned short*)(smem + LO_A2 + w * 528 + j * 2));
          den += ea;
        }
        cnew = num / den;
      } else {
        cnew = (1.f - i_s) * ringC[((t - 1) & 7) * 256 + j] + i_s * g_t;
      }
      const float hnew = o_s * tanhf(cnew);
      ringC[(t & 7) * 256 + j] = cnew;
      ((unsigned short*)(smem + LO_A1))[j] = (unsigned short)f2bf(hnew);
      if (side == 0) hseq[((size_t)dir * TSEQ + t) * H + j] = hnew;
    }
    if (wv == 7) {
      int mAll[8], sAll[8];
#pragma unroll
      for (int s = 0; s < 8; ++s) { mAll[s] = __shfl(nmt, s); sAll[s] = __shfl(nmt, 8 + s); }
      if (lane == 0) {
        int* mq = metaI + ((t + 1) & 1) * 32;
        int n = 0;
        for (int s = 0; s < 8; ++s)
          if (mAll[s]) { mq[1 + n] = s; mq[9 + n] = sAll[s]; ++n; }
        mq[0] = n;
      }
    }
    cxI = nxI; cxO = nxO; cxG = nxG; cxA = nxA;
    __syncthreads();   // bar6: A1/ringC/meta ready for t+1
  }
}

// ---------------- K4: output projection -------------------------------------
__global__ __launch_bounds__(64) void k_proj(
    const float* __restrict__ hseq, const float* __restrict__ W_lin,
    const float* __restrict__ b_lin, float* __restrict__ out)
{
  const int t = blockIdx.x;
  const int tid = threadIdx.x;
  __shared__ float hrow[2 * H];
  for (int i = tid; i < H; i += 64) {
    hrow[i]     = hseq[(size_t)t * H + i];
    hrow[H + i] = hseq[((size_t)TSEQ + (TSEQ - 1 - t)) * H + i];
  }
  __syncthreads();
  if (tid < CCLS) {
    float acc = b_lin[tid];
    for (int j = 0; j < 2 * H; ++j) acc += hrow[j] * W_lin[(size_t)j * CCLS + tid];
    out[(size_t)t * CCLS + tid] = acc;
  }
}

// ---------------------------------------------------------------------------
extern "C" void kernel_launch(void* const* d_in, const int* in_sizes, int n_in,
                              void* d_out, int out_size, void* d_ws, size_t ws_size,
                              hipStream_t stream)
{
  const int* inputs   = (const int*)d_in[0];
  const int* fw_ids   = (const int*)d_in[1];
  const int* fw_start = (const int*)d_in[2];
  const int* fw_mask  = (const int*)d_in[3];
  const int* bw_ids   = (const int*)d_in[4];
  const int* bw_start = (const int*)d_in[5];
  const int* bw_mask  = (const int*)d_in[6];
  const float* E          = (const float*)d_in[8];
  const float* word_table = (const float*)d_in[9];
  const float* W_lin      = (const float*)d_in[10];
  const float* b_lin      = (const float*)d_in[11];
  const float* fw_W_ih  = (const float*)d_in[12];
  const float* fw_W_hh  = (const float*)d_in[13];
  const float* fw_b     = (const float*)d_in[14];
  const float* fw_aW_ih = (const float*)d_in[15];
  const float* fw_aW_hh = (const float*)d_in[16];
  const float* fw_ab    = (const float*)d_in[17];
  const float* fw_wW_ih = (const float*)d_in[18];
  const float* fw_wW_hh = (const float*)d_in[19];
  const float* fw_wb    = (const float*)d_in[20];
  const float* bw_W_ih  = (const float*)d_in[21];
  const float* bw_W_hh  = (const float*)d_in[22];
  const float* bw_b     = (const float*)d_in[23];
  const float* bw_aW_ih = (const float*)d_in[24];
  const float* bw_aW_hh = (const float*)d_in[25];
  const float* bw_ab    = (const float*)d_in[26];
  const float* bw_wW_ih = (const float*)d_in[27];
  const float* bw_wW_hh = (const float*)d_in[28];
  const float* bw_wb    = (const float*)d_in[29];

  char* p = (char*)d_ws;
  __hip_bfloat16* xg = (__hip_bfloat16*)p;  p += (size_t)2 * TSEQ * H3 * 2;        // 6.3 MB
  float* xa   = (float*)p;                  p += (size_t)2 * TSEQ * H * 4;         // 4.2 MB
  float* hseq = (float*)p;                  p += (size_t)2 * TSEQ * H * 4;         // 4.2 MB
  __hip_bfloat16* wg = (__hip_bfloat16*)p;  p += (size_t)2 * TSEQ * KEND * H3 * 2; // 50.3 MB
  unsigned short* Wpk = (unsigned short*)p; p += (size_t)2 * 112 * 8 * 512 * 2;    // 1.8 MB
  unsigned short* xb = (unsigned short*)p;  p += (size_t)2 * 2 * 2 * 768 * 2;      // 12 KB
  unsigned* xf = (unsigned*)p;              p += 512;

  hipFuncSetAttribute((const void*)k_scan,
                      hipFuncAttributeMaxDynamicSharedMemorySize, SMEM_SCAN);
  hipMemsetAsync(xf, 0, 512, stream);

  k_pack<<<dim3(112, 2), 64, 0, stream>>>(
      fw_W_hh, fw_wW_hh, fw_aW_hh, bw_W_hh, bw_wW_hh, bw_aW_hh, Wpk);
  k_embed<<<dim3(TSEQ, 2), 256, 0, stream>>>(
      inputs, E, fw_W_ih, fw_b, fw_aW_ih, fw_ab, bw_W_ih, bw_b, bw_aW_ih, bw_ab, xg, xa);
  k_wordgates<<<dim3(TSEQ, 2), 256, 0, stream>>>(
      fw_ids, fw_mask, bw_ids, bw_mask, word_table, fw_wW_ih, fw_wb, bw_wW_ih, bw_wb, wg);
  k_scan<<<4, NTH, SMEM_SCAN, stream>>>(
      xg, xa, wg, hseq, fw_start, fw_mask, bw_start, bw_mask, Wpk, xb, xf);
  k_proj<<<TSEQ, 64, 0, stream>>>(hseq, W_lin, b_lin, (float*)d_out);
}

// Round 8
// 14366.812 us; speedup vs baseline: 3.5747x; 1.4754x over previous
//
#include <hip/hip_runtime.h>
#include <hip/hip_bf16.h>

// ---------------------------------------------------------------------------
// Lattice LSTM (bidirectional) — round 7: builtin-MFMA weight residency at
// 1 wave/SIMD (512 unified regs/wave) + same-XCD exchange pairing.
//
//   2 CUs per direction: side0 owns v = h@W_hh (48 tiles), side1 owns
//   u = h@wW_hh (48 tiles); 12 tiles/wave (384 regs) held by the BUILTIN
//   MFMA path (round-4-proven numerics) under __launch_bounds__(256,1).
//   aW_hh (16 tiles) in LDS on both sides; word cells/alpha/merge redundant.
//
//   Exchange partners are gid pairs {0,8} and {1,9}: under round-robin
//   block->XCD dispatch (bid%8), both partners share an XCD/L2, cutting the
//   per-step flag+payload round trip from cross-die to local-L2 latency.
// ---------------------------------------------------------------------------

#define TSEQ 2048
#define KEND 8
#define DEMB 100
#define H    256
#define H3   768
#define WD   300
#define CCLS 18
#define NTH  256

typedef __attribute__((ext_vector_type(8))) short bf16x8;
typedef __attribute__((ext_vector_type(4))) float f32x4;

// LDS offsets (bytes)
#define LO_AT  0        // alpha weight tiles [16][8 ks][64 lanes][16B] 131072
#define LO_A1  131072   // h(t-1) row bf16[256]                            512
#define LO_VS  131584   // v stage bf16[768]                              1536
#define LO_UR  133120   // u-ring bf16 [7][768]                          10752
#define LO_RC  143872   // ringC f32 [8][256]                             8192
#define LO_A2  152064   // cw rows bf16 [8][264] (528B stride)            4224
#define LO_AWS 156288   // awS bf16 [8][256]                              4096
#define LO_MT  160384   // meta int [2][32]: {nw, slot[8], start[8]}       256
#define SMEM_SCAN 160640

__device__ __forceinline__ float sigf(float x) { return 1.0f / (1.0f + expf(-x)); }
__device__ __forceinline__ float bf2f(unsigned u) { return __uint_as_float(u << 16); }
__device__ __forceinline__ unsigned f2bf(float f) {
  union { float f; unsigned u; } x; x.f = f;
  unsigned r = x.u + 0x7fffu + ((x.u >> 16) & 1u);   // RNE
  return r >> 16;
}

// ---------------- K0: pack weights into MFMA-fragment layout (bf16) ---------
__global__ __launch_bounds__(64) void k_pack(
    const float* __restrict__ W_hh_f, const float* __restrict__ wW_hh_f, const float* __restrict__ aW_hh_f,
    const float* __restrict__ W_hh_b, const float* __restrict__ wW_hh_b, const float* __restrict__ aW_hh_b,
    unsigned short* __restrict__ Wpk)
{
  const int T = blockIdx.x, dir = blockIdx.y;
  const int lane = threadIdx.x;
  const float* Wg = dir ? W_hh_b  : W_hh_f;
  const float* Ww = dir ? wW_hh_b : wW_hh_f;
  const float* Wa = dir ? aW_hh_b : aW_hh_f;
  for (int ks = 0; ks < 8; ++ks) {
    bf16x8 sv;
#pragma unroll
    for (int e = 0; e < 8; ++e) {
      const int k = ks * 32 + (lane >> 4) * 8 + e;
      float f;
      if (T < 96) {
        const int c = T * 16 + (lane & 15);
        f = (c < H3) ? Wg[(size_t)k * H3 + c] : Ww[(size_t)k * H3 + (c - H3)];
      } else {
        const int c = (T - 96) * 16 + (lane & 15);
        f = Wa[(size_t)k * H + c];
      }
      sv[e] = (short)f2bf(f);
    }
    *(bf16x8*)(Wpk + (((size_t)dir * 112 + T) * 8 + ks) * 512 + lane * 8) = sv;
  }
}

// ---------------- K1: char embedding -> gate / alpha input preacts ----------
__global__ __launch_bounds__(256) void k_embed(
    const int* __restrict__ inputs, const float* __restrict__ E,
    const float* __restrict__ W_ih_f, const float* __restrict__ b_f,
    const float* __restrict__ aW_ih_f, const float* __restrict__ ab_f,
    const float* __restrict__ W_ih_b, const float* __restrict__ b_b,
    const float* __restrict__ aW_ih_b, const float* __restrict__ ab_b,
    __hip_bfloat16* __restrict__ xg, float* __restrict__ xa)
{
  const int t = blockIdx.x, dir = blockIdx.y;
  const int tid = threadIdx.x;
  const float* W_ih = dir ? W_ih_b : W_ih_f;
  const float* bb   = dir ? b_b    : b_f;
  const float* aW   = dir ? aW_ih_b : aW_ih_f;
  const float* ab   = dir ? ab_b   : ab_f;
  const int src = dir ? (TSEQ - 1 - t) : t;

  __shared__ float xr[DEMB];
  if (tid < DEMB) xr[tid] = E[(size_t)inputs[src] * DEMB + tid];
  __syncthreads();

  float a0 = bb[tid], a1 = bb[H + tid], a2 = bb[2 * H + tid], a3 = ab[tid];
  for (int r = 0; r < DEMB; r += 4) {
    const float4 e4 = *reinterpret_cast<const float4*>(&xr[r]);
    const float ev[4] = {e4.x, e4.y, e4.z, e4.w};
#pragma unroll
    for (int kk = 0; kk < 4; ++kk) {
      const float* wp = W_ih + (size_t)(r + kk) * H3 + tid;
      a0 += ev[kk] * wp[0];
      a1 += ev[kk] * wp[H];
      a2 += ev[kk] * wp[2 * H];
      a3 += ev[kk] * aW[(size_t)(r + kk) * H + tid];
    }
  }
  __hip_bfloat16* xgrow = xg + ((size_t)dir * TSEQ + t) * H3;
  xgrow[tid]         = __float2bfloat16(a0);
  xgrow[H + tid]     = __float2bfloat16(a1);
  xgrow[2 * H + tid] = __float2bfloat16(a2);
  xa[((size_t)dir * TSEQ + t) * H + tid] = a3;
}

// ---------------- K2: word-gate preacts (valid slots only), bf16 out --------
__global__ __launch_bounds__(256) void k_wordgates(
    const int* __restrict__ fw_ids, const int* __restrict__ fw_mask,
    const int* __restrict__ bw_ids, const int* __restrict__ bw_mask,
    const float* __restrict__ word_table,
    const float* __restrict__ wW_ih_f, const float* __restrict__ wb_f,
    const float* __restrict__ wW_ih_b, const float* __restrict__ wb_b,
    __hip_bfloat16* __restrict__ wg)
{
  const int t = blockIdx.x, dir = blockIdx.y;
  const int tid = threadIdx.x;
  const int* ids = (dir ? bw_ids : fw_ids) + t * KEND;
  const int* msk = (dir ? bw_mask : fw_mask) + t * KEND;
  const float* wW = dir ? wW_ih_b : wW_ih_f;
  const float* wb = dir ? wb_b    : wb_f;

  __shared__ float we[KEND][WD];
  for (int w = 0; w < KEND; ++w) {
    if (msk[w]) {
      const float* src = word_table + (size_t)ids[w] * WD;
      for (int i = tid; i < WD; i += 256) we[w][i] = src[i];
    }
  }
  __syncthreads();

  __hip_bfloat16* out = wg + ((size_t)dir * TSEQ + t) * KEND * H3;
  for (int w = 0; w < KEND; ++w) {
    if (!msk[w]) continue;
    float a0 = wb[tid], a1 = wb[H + tid], a2 = wb[2 * H + tid];
    for (int r = 0; r < WD; r += 4) {
      const float4 e4 = *reinterpret_cast<const float4*>(&we[w][r]);
      const float ev[4] = {e4.x, e4.y, e4.z, e4.w};
#pragma unroll
      for (int kk = 0; kk < 4; ++kk) {
        const float* wp = wW + (size_t)(r + kk) * H3 + tid;
        a0 += ev[kk] * wp[0];
        a1 += ev[kk] * wp[H];
        a2 += ev[kk] * wp[2 * H];
      }
    }
    out[w * H3 + tid]         = __float2bfloat16(a0);
    out[w * H3 + H + tid]     = __float2bfloat16(a1);
    out[w * H3 + 2 * H + tid] = __float2bfloat16(a2);
  }
}

// ---------------- K3: scan; active blocks {0,8}=dir0, {1,9}=dir1 ------------
__global__ __launch_bounds__(NTH, 1) void k_scan(
    const __hip_bfloat16* __restrict__ xg, const float* __restrict__ xa,
    const __hip_bfloat16* __restrict__ wgG, float* __restrict__ hseq,
    const int* __restrict__ fw_start, const int* __restrict__ fw_mask,
    const int* __restrict__ bw_start, const int* __restrict__ bw_mask,
    const unsigned short* __restrict__ Wpk,
    unsigned long long* __restrict__ xb, unsigned* __restrict__ xf)
{
  const int gid = blockIdx.x;
  if (gid != 0 && gid != 1 && gid != 8 && gid != 9) return;  // same-XCD pairs
  const int dir  = gid & 1;
  const int side = gid >> 3;

  extern __shared__ char smem[];
  unsigned short* A1_16 = (unsigned short*)(smem + LO_A1);
  unsigned short* vS16  = (unsigned short*)(smem + LO_VS);
  unsigned short* ur16  = (unsigned short*)(smem + LO_UR);
  float* ringC = (float*)(smem + LO_RC);
  unsigned short* awS16 = (unsigned short*)(smem + LO_AWS);
  int* metaI = (int*)(smem + LO_MT);

  const int tid  = threadIdx.x;
  const int lane = tid & 63;
  const int wv   = tid >> 6;          // wave 0..3
  const int lmod = lane & 15;
  const int lgrp = lane >> 4;

  const int* startA = dir ? bw_start : fw_start;
  const int* maskA  = dir ? bw_mask  : fw_mask;
  const char* WpkD = (const char*)(Wpk + (size_t)dir * 112 * 8 * 512);

  unsigned long long* myPay = xb + (size_t)((dir * 2 + side) * 2) * 192;
  const unsigned long long* peerPay = xb + (size_t)((dir * 2 + (side ^ 1)) * 2) * 192;
  unsigned* myFlag   = xf + (dir * 2 + side) * 32;
  unsigned* peerFlag = xf + (dir * 2 + (side ^ 1)) * 32;

  // ---- one-time: 12 gate tiles/wave -> registers (builtin MFMA path) -------
  bf16x8 rW[12][8];
  {
    const char* rp = WpkD + (size_t)(side * 48 + wv * 12) * 8192 + lane * 16;
#pragma unroll
    for (int n = 0; n < 12; ++n)
#pragma unroll
      for (int ks = 0; ks < 8; ++ks)
        rW[n][ks] = *(const bf16x8*)(rp + (n * 8 + ks) * 1024);
  }
  // ---- one-time: 16 alpha tiles -> LDS -------------------------------------
  for (int o = tid * 16; o < 131072; o += NTH * 16)
    *(uint4*)(smem + LO_AT + o) = *(const uint4*)(WpkD + (size_t)96 * 8192 + o);
  // zero A1 / A2 / ringC
  if (tid < 32) *(uint4*)(smem + LO_A1 + tid * 16) = uint4{0, 0, 0, 0};
  for (int o = tid * 16; o < 4224; o += NTH * 16)
    *(uint4*)(smem + LO_A2 + o) = uint4{0, 0, 0, 0};
  for (int o = tid * 16; o < 8192; o += NTH * 16)
    *(uint4*)(smem + LO_RC + o) = uint4{0, 0, 0, 0};

  // ---- prologue: prefetch t=0, compact meta[0] -----------------------------
  unsigned nxI = 0, nxO = 0, nxG = 0; float nxA = 0.f;
  unsigned cxI = 0, cxO = 0, cxG = 0; float cxA = 0.f;
  int nmt = 0;
  {
    const unsigned short* xr = (const unsigned short*)(xg + (size_t)dir * TSEQ * H3);
    nxI = xr[tid]; nxO = xr[H + tid]; nxG = xr[2 * H + tid];
    nxA = xa[(size_t)dir * TSEQ * H + tid];
    if (wv == 3) {
      if (lane < 8) nmt = maskA[lane];
      else if (lane < 16) nmt = startA[lane - 8];
    }
  }
  __syncthreads();
  if (wv == 3) {
    int mAll[8], sAll[8];
#pragma unroll
    for (int s = 0; s < 8; ++s) { mAll[s] = __shfl(nmt, s); sAll[s] = __shfl(nmt, 8 + s); }
    if (lane == 0) {
      int n = 0;
      for (int s = 0; s < 8; ++s)
        if (mAll[s]) { metaI[1 + n] = s; metaI[9 + n] = sAll[s]; ++n; }
      metaI[0] = n;
    }
  }
  cxI = nxI; cxO = nxO; cxG = nxG; cxA = nxA;
  __syncthreads();

  // ---- main loop -----------------------------------------------------------
  for (int t = 0; t < TSEQ; ++t) {
    const int par = t & 1;
    const int* mp = metaI + par * 32;
    const int nw = mp[0];
    const int us7 = (t + 6) % 7;                    // slot for s = t-1
    unsigned short* stage16 = side ? (ur16 + us7 * 768) : vS16;
    unsigned short* rcv16   = side ? vS16 : (ur16 + us7 * 768);

    // -- issue wg(t) loads for this step's word cells (registers) ------------
    unsigned short wgv[24];
#pragma unroll
    for (int it = 0; it < 8; ++it) {
      const int u0 = tid + it * NTH;
      if (u0 < nw * 256) {
        const int w = u0 >> 8, j = u0 & 255;
        const int slot = mp[1 + w];
        const unsigned short* wgp =
            (const unsigned short*)wgG + ((size_t)(dir * TSEQ + t) * KEND + slot) * H3 + j;
        wgv[it * 3 + 0] = wgp[0];
        wgv[it * 3 + 1] = wgp[256];
        wgv[it * 3 + 2] = wgp[512];
      }
    }

    // ======== S1: own half of [v|u] = h(t-1) @ W  (2 groups of 6 tiles) =====
#pragma unroll
    for (int g = 0; g < 2; ++g) {
      f32x4 acc[6];
#pragma unroll
      for (int n = 0; n < 6; ++n) acc[n] = f32x4{0.f, 0.f, 0.f, 0.f};
#pragma unroll
      for (int ks = 0; ks < 8; ++ks) {
        const bf16x8 av = *(const bf16x8*)(smem + LO_A1 + ks * 64 + lgrp * 16);
#pragma unroll
        for (int n = 0; n < 6; ++n)
          acc[n] = __builtin_amdgcn_mfma_f32_16x16x32_bf16(av, rW[g * 6 + n][ks], acc[n], 0, 0, 0);
      }
      if (lane < 16) {
#pragma unroll
        for (int n = 0; n < 6; ++n)
          stage16[(wv * 12 + g * 6 + n) * 16 + lane] = (unsigned short)f2bf(acc[n][0]);
      }
    }
    __syncthreads();   // bar1: stage complete

    // -- publish (192x8B agent atomics) + prefetch t+1 + S2a -----------------
    if (tid < 192) {
      const unsigned long long q = *(const unsigned long long*)((const char*)stage16 + tid * 8);
      __hip_atomic_store(myPay + par * 192 + tid, q, __ATOMIC_RELAXED, __HIP_MEMORY_SCOPE_AGENT);
    }
    {
      const int tn = (t + 1 < TSEQ) ? t + 1 : TSEQ - 1;
      const unsigned short* xr = (const unsigned short*)(xg + ((size_t)dir * TSEQ + tn) * H3);
      nxI = xr[tid]; nxO = xr[H + tid]; nxG = xr[2 * H + tid];
      nxA = xa[((size_t)dir * TSEQ + tn) * H + tid];
      if (wv == 3) {
        if (lane < 8) nmt = maskA[tn * KEND + lane];
        else if (lane < 16) nmt = startA[tn * KEND + (lane - 8)];
      }
    }
    // S2a: side1 = all words (has own u[t-1]); side0 = starts <= t-2 only
#pragma unroll
    for (int it = 0; it < 8; ++it) {
      const int u0 = tid + it * NTH;
      if (u0 < nw * 256) {
        const int w = u0 >> 8, j = u0 & 255;
        const int s = mp[9 + w];
        if (side == 1 || s != t - 1) {
          const unsigned short* ur = ur16 + (s % 7) * 768;
          const float wi  = bf2f(wgv[it * 3 + 0]) + bf2f(ur[j]);
          const float wf  = bf2f(wgv[it * 3 + 1]) + bf2f(ur[256 + j]);
          const float wgg = bf2f(wgv[it * 3 + 2]) + bf2f(ur[512 + j]);
          const float cs  = ringC[(s & 7) * 256 + j];
          const float cv  = sigf(wf) * cs + sigf(wi) * tanhf(wgg);
          *(unsigned short*)(smem + LO_A2 + w * 528 + j * 2) = (unsigned short)f2bf(cv);
        }
      }
    }
    __syncthreads();   // bar2: publish stores drained (vmcnt), S2a done

    if (tid == 0) {
      __hip_atomic_store(myFlag, (unsigned)(t + 1), __ATOMIC_RELAXED, __HIP_MEMORY_SCOPE_AGENT);
      while (__hip_atomic_load(peerFlag, __ATOMIC_RELAXED, __HIP_MEMORY_SCOPE_AGENT) < (unsigned)(t + 1))
        __builtin_amdgcn_s_sleep(1);
    }
    __syncthreads();   // bar3: peer payload published

    if (tid < 192) {
      const unsigned long long q =
          __hip_atomic_load(peerPay + par * 192 + tid, __ATOMIC_RELAXED, __HIP_MEMORY_SCOPE_AGENT);
      *(unsigned long long*)((char*)rcv16 + tid * 8) = q;
    }
    __syncthreads();   // bar4: vS + u(t-1) complete on both sides

    // ======== S2b: side0, len-2 words (start == t-1) ========================
    if (side == 0) {
#pragma unroll
      for (int it = 0; it < 8; ++it) {
        const int u0 = tid + it * NTH;
        if (u0 < nw * 256) {
          const int w = u0 >> 8, j = u0 & 255;
          const int s = mp[9 + w];
          if (s == t - 1) {
            const unsigned short* ur = ur16 + (s % 7) * 768;
            const float wi  = bf2f(wgv[it * 3 + 0]) + bf2f(ur[j]);
            const float wf  = bf2f(wgv[it * 3 + 1]) + bf2f(ur[256 + j]);
            const float wgg = bf2f(wgv[it * 3 + 2]) + bf2f(ur[512 + j]);
            const float cs  = ringC[(s & 7) * 256 + j];
            const float cv  = sigf(wf) * cs + sigf(wi) * tanhf(wgg);
            *(unsigned short*)(smem + LO_A2 + w * 528 + j * 2) = (unsigned short)f2bf(cv);
          }
        }
      }
    }
    __syncthreads();   // bar5: A2 (cw) ready

    // ======== S3: alpha matvec aw = cw @ aW_hh (4 LDS tiles/wave) ===========
    if (nw > 0) {
      const int r2 = (lmod > 7) ? 7 : lmod;
      f32x4 ac[4];
#pragma unroll
      for (int m = 0; m < 4; ++m) ac[m] = f32x4{0.f, 0.f, 0.f, 0.f};
#pragma unroll
      for (int ks = 0; ks < 8; ++ks) {
        const bf16x8 a2v = *(const bf16x8*)(smem + LO_A2 + r2 * 528 + ks * 64 + lgrp * 16);
#pragma unroll
        for (int m = 0; m < 4; ++m) {
          const bf16x8 b = *(const bf16x8*)(smem + LO_AT + (size_t)(wv * 4 + m) * 8192 + ks * 1024 + lane * 16);
          ac[m] = __builtin_amdgcn_mfma_f32_16x16x32_bf16(a2v, b, ac[m], 0, 0, 0);
        }
      }
#pragma unroll
      for (int m = 0; m < 4; ++m) {
#pragma unroll
        for (int r = 0; r < 4; ++r) {
          const int row = lgrp * 4 + r;
          if (row < nw) awS16[row * 256 + (wv * 4 + m) * 16 + lmod] = (unsigned short)f2bf(ac[m][r]);
        }
      }
    }
    __syncthreads();   // bar6: awS ready

    // ======== S4: merge + state update (redundant, bit-identical) ===========
    {
      const int j = tid;
      const float i_s = sigf(bf2f(cxI) + bf2f(vS16[j]));
      const float o_s = sigf(bf2f(cxO) + bf2f(vS16[256 + j]));
      const float g_t = tanhf(bf2f(cxG) + bf2f(vS16[512 + j]));
      float cnew;
      if (nw > 0) {
        const float e_i = expf(i_s);
        float num = e_i * g_t, den = e_i;
        for (int w = 0; w < nw; ++w) {
          const float a  = sigf(cxA + bf2f(awS16[w * 256 + j]));
          const float ea = expf(a);
          num += ea * bf2f(*(const unsigned short*)(smem + LO_A2 + w * 528 + j * 2));
          den += ea;
        }
        cnew = num / den;
      } else {
        cnew = (1.f - i_s) * ringC[((t - 1) & 7) * 256 + j] + i_s * g_t;
      }
      const float hnew = o_s * tanhf(cnew);
      ringC[(t & 7) * 256 + j] = cnew;
      A1_16[j] = (unsigned short)f2bf(hnew);
      if (side == 0) hseq[((size_t)dir * TSEQ + t) * H + j] = hnew;
    }
    if (wv == 3) {
      int mAll[8], sAll[8];
#pragma unroll
      for (int s = 0; s < 8; ++s) { mAll[s] = __shfl(nmt, s); sAll[s] = __shfl(nmt, 8 + s); }
      if (lane == 0) {
        int* mq = metaI + ((t + 1) & 1) * 32;
        int n = 0;
        for (int s = 0; s < 8; ++s)
          if (mAll[s]) { mq[1 + n] = s; mq[9 + n] = sAll[s]; ++n; }
        mq[0] = n;
      }
    }
    cxI = nxI; cxO = nxO; cxG = nxG; cxA = nxA;
    __syncthreads();   // bar7: A1/ringC/meta ready for t+1
  }
}

// ---------------- K4: output projection -------------------------------------
__global__ __launch_bounds__(64) void k_proj(
    const float* __restrict__ hseq, const float* __restrict__ W_lin,
    const float* __restrict__ b_lin, float* __restrict__ out)
{
  const int t = blockIdx.x;
  const int tid = threadIdx.x;
  __shared__ float hrow[2 * H];
  for (int i = tid; i < H; i += 64) {
    hrow[i]     = hseq[(size_t)t * H + i];
    hrow[H + i] = hseq[((size_t)TSEQ + (TSEQ - 1 - t)) * H + i];
  }
  __syncthreads();
  if (tid < CCLS) {
    float acc = b_lin[tid];
    for (int j = 0; j < 2 * H; ++j) acc += hrow[j] * W_lin[(size_t)j * CCLS + tid];
    out[(size_t)t * CCLS + tid] = acc;
  }
}

// ---------------------------------------------------------------------------
extern "C" void kernel_launch(void* const* d_in, const int* in_sizes, int n_in,
                              void* d_out, int out_size, void* d_ws, size_t ws_size,
                              hipStream_t stream)
{
  const int* inputs   = (const int*)d_in[0];
  const int* fw_ids   = (const int*)d_in[1];
  const int* fw_start = (const int*)d_in[2];
  const int* fw_mask  = (const int*)d_in[3];
  const int* bw_ids   = (const int*)d_in[4];
  const int* bw_start = (const int*)d_in[5];
  const int* bw_mask  = (const int*)d_in[6];
  const float* E          = (const float*)d_in[8];
  const float* word_table = (const float*)d_in[9];
  const float* W_lin      = (const float*)d_in[10];
  const float* b_lin      = (const float*)d_in[11];
  const float* fw_W_ih  = (const float*)d_in[12];
  const float* fw_W_hh  = (const float*)d_in[13];
  const float* fw_b     = (const float*)d_in[14];
  const float* fw_aW_ih = (const float*)d_in[15];
  const float* fw_aW_hh = (const float*)d_in[16];
  const float* fw_ab    = (const float*)d_in[17];
  const float* fw_wW_ih = (const float*)d_in[18];
  const float* fw_wW_hh = (const float*)d_in[19];
  const float* fw_wb    = (const float*)d_in[20];
  const float* bw_W_ih  = (const float*)d_in[21];
  const float* bw_W_hh  = (const float*)d_in[22];
  const float* bw_b     = (const float*)d_in[23];
  const float* bw_aW_ih = (const float*)d_in[24];
  const float* bw_aW_hh = (const float*)d_in[25];
  const float* bw_ab    = (const float*)d_in[26];
  const float* bw_wW_ih = (const float*)d_in[27];
  const float* bw_wW_hh = (const float*)d_in[28];
  const float* bw_wb    = (const float*)d_in[29];

  char* p = (char*)d_ws;
  __hip_bfloat16* xg = (__hip_bfloat16*)p;  p += (size_t)2 * TSEQ * H3 * 2;        // 6.3 MB
  float* xa   = (float*)p;                  p += (size_t)2 * TSEQ * H * 4;         // 4.2 MB
  float* hseq = (float*)p;                  p += (size_t)2 * TSEQ * H * 4;         // 4.2 MB
  __hip_bfloat16* wg = (__hip_bfloat16*)p;  p += (size_t)2 * TSEQ * KEND * H3 * 2; // 50.3 MB
  unsigned short* Wpk = (unsigned short*)p; p += (size_t)2 * 112 * 8 * 512 * 2;    // 1.8 MB
  unsigned long long* xb = (unsigned long long*)p; p += (size_t)2 * 2 * 2 * 192 * 8; // 12 KB
  unsigned* xf = (unsigned*)p;              p += 512;

  hipFuncSetAttribute((const void*)k_scan,
                      hipFuncAttributeMaxDynamicSharedMemorySize, SMEM_SCAN);
  hipMemsetAsync(xf, 0, 512, stream);

  k_pack<<<dim3(112, 2), 64, 0, stream>>>(
      fw_W_hh, fw_wW_hh, fw_aW_hh, bw_W_hh, bw_wW_hh, bw_aW_hh, Wpk);
  k_embed<<<dim3(TSEQ, 2), 256, 0, stream>>>(
      inputs, E, fw_W_ih, fw_b, fw_aW_ih, fw_ab, bw_W_ih, bw_b, bw_aW_ih, bw_ab, xg, xa);
  k_wordgates<<<dim3(TSEQ, 2), 256, 0, stream>>>(
      fw_ids, fw_mask, bw_ids, bw_mask, word_table, fw_wW_ih, fw_wb, bw_wW_ih, bw_wb, wg);
  k_scan<<<16, NTH, SMEM_SCAN, stream>>>(
      xg, xa, wg, hseq, fw_start, fw_mask, bw_start, bw_mask, Wpk, xb, xf);
  k_proj<<<TSEQ, 64, 0, stream>>>(hseq, W_lin, b_lin, (float*)d_out);
}